// Round 13
// baseline (318.120 us; speedup 1.0000x reference)
//
#include <hip/hip_runtime.h>
#include <hip/hip_bf16.h>

// Problem constants (fixed by setup_inputs)
#define M_ROWS 262144   // B*A*T = 16*64*256
#define TILE_M 64
#define BK 32
#define INVM (1.0f / 262144.0f)

typedef unsigned short ushort_t;
typedef unsigned int uint_t;
typedef __attribute__((ext_vector_type(8))) short short8_t;   // 8 bf16 = 4 VGPRs
typedef __attribute__((ext_vector_type(4))) float float4_t;   // MFMA acc

// Raw barriers with PRECISE waits (T4): __syncthreads() drains vmcnt(0) and
// kills the async-DMA prefetch window at every barrier. LDS-only hazards need
// only lgkmcnt(0); the in-flight DMA (targets the OTHER Abuf half) and the
// C-stores (never re-read) are disjoint, so vmcnt stays in flight across the
// 5 intra-tile barriers and drains once per tile at loop-top.
#define BAR_LGKM do { asm volatile("s_waitcnt lgkmcnt(0)" ::: "memory"); \
                      __builtin_amdgcn_s_barrier(); } while (0)
#define BAR_ALL  do { asm volatile("s_waitcnt vmcnt(0) lgkmcnt(0)" ::: "memory"); \
                      __builtin_amdgcn_s_barrier(); } while (0)

// bf16 (stored as ushort) <-> fp32 helpers. Load is exact; store is RNE.
__device__ __forceinline__ float b2f(ushort_t u) {
    union { uint_t i; float f; } c; c.i = ((uint_t)u) << 16; return c.f;
}
__device__ __forceinline__ ushort_t f2b(float f) {
    union { float f; uint_t i; } c; c.f = f;
    uint_t u = c.i;
    return (ushort_t)((u + 0x7fffu + ((u >> 16) & 1u)) >> 16);
}
// packed 2xfp32 -> 2xbf16 (v_cvt_pk_bf16_f32 on gfx950, RNE)
__device__ __forceinline__ uint_t pack2(float a, float b) {
    union { __hip_bfloat162 h; uint_t u; } c;
    c.h = __float22bfloat162_rn(make_float2(a, b));
    return c.u;
}

// async global->LDS DMA, 16 B per lane; data lands at ldsbase + lane*16
__device__ __forceinline__ void gld_lds16(const ushort_t* g, ushort_t* l) {
    __builtin_amdgcn_global_load_lds((const __attribute__((address_space(1))) void*)g,
                                     (__attribute__((address_space(3))) void*)l, 16, 0, 0);
}

// BN finalize arithmetic (shared by all consumers): from accumulated sum/sumsq.
__device__ __forceinline__ void bn_coeff(float s, float q, float g, float be,
                                         float& sc, float& sh) {
    float mean = s * INVM;
    float var = q * INVM - mean * mean;
    sc = g * rsqrtf(var + 1e-5f);
    sh = fmaf(-mean, sc, be);
}

// ---------------------------------------------------------------------------
// Layer-1 N-SPLIT pipelined GEMM with FUSED causal-cummax:
//   C = [bnrelu0(X), cummax(bnrelu0(X))] @ W1 + b1  (K=256), X read ONCE.
// Grid = 1024 blocks: blockIdx = tile*2 + nhalf; each block = 64-col half of
// N=128 over RPT=8 row-tiles (512 rows = 2 whole sequences, in order).
// Per tile: PASS1 = act whole tile IN PLACE (once per element) + local 16-row
// scan into regs + group totals -> kt0 MFMA reads PRE-ACTIVATED frags ->
// PASS2 = prefix-combine + write P in place (+carry) -> kt1 MFMA on P frags.
// Raw barriers: only loop-top drains vmcnt -> DMA prefetch spans whole tile.
// BN coeffs computed in-block from accumIn; stats atomicAdd into accumOut.
// ---------------------------------------------------------------------------
template<int RPT>
__launch_bounds__(256)
__global__ void gemm1s_k(const ushort_t* __restrict__ X,
                         const ushort_t* __restrict__ WT, const float* __restrict__ bias,
                         const float* __restrict__ g, const float* __restrict__ be,
                         const float* __restrict__ accumIn,
                         ushort_t* __restrict__ C, float* __restrict__ accumOut) {
    __shared__ __attribute__((aligned(16))) ushort_t Bs[64 * 256];       // 32 KB
    __shared__ __attribute__((aligned(16))) ushort_t Abuf[2][64 * 128];  // 2x16 KB
    __shared__ float sred[4 * 64 * 2];
    __shared__ float s_sc[128], s_sh[128];
    __shared__ float gtb[4 * 128];    // scan group totals
    __shared__ float carry[128];      // inter-tile scan carry

    const int tid = threadIdx.x;
    const int lane = tid & 63;
    const int wave = tid >> 6;
    const int wm = wave & 1, wn = wave >> 1;
    const int quad = lane >> 4, l16 = lane & 15;
    const int srow = lane >> 4, sp16 = lane & 15;   // A staging
    const int brow = lane >> 5, bs32 = lane & 31;   // B staging (512 B rows)
    const int tileId = blockIdx.x >> 1;
    const int n0 = (blockIdx.x & 1) * 64;           // column-half offset
    const int row0 = tileId * (RPT * 64);

    if (tid < 128) {
        float sc, sh;
        bn_coeff(accumIn[tid], accumIn[128 + tid], g[tid], be[tid], sc, sh);
        s_sc[tid] = sc; s_sh[tid] = sh;
    }

    // ---- stage B half (rows n0..n0+63 of WT, 512 B each): 32 chunks x 1 KB ----
    #pragma unroll
    for (int i = 0; i < 8; ++i) {
        int t = i * 4 + wave;
        int r = t * 2 + brow;                        // local B row 0..63
        int sp = (bs32 & 16) | ((bs32 ^ r) & 15);    // half-preserving XOR swizzle
        gld_lds16(WT + (size_t)(n0 + r) * 256 + sp * 8, Bs + t * 512);
    }

    auto stageX = [&](int it, int buf) {
        int r0 = row0 + it * 64;
        #pragma unroll
        for (int i = 0; i < 4; ++i) {
            int t = i * 4 + wave;
            int r = t * 4 + srow;
            int sp = sp16 ^ (r & 15);
            gld_lds16(X + (size_t)(r0 + r) * 128 + sp * 8, Abuf[buf] + t * 512);
        }
    };
    stageX(0, 0);

    float bvs[2];
    #pragma unroll
    for (int nt = 0; nt < 2; ++nt) bvs[nt] = bias[n0 + wn * 32 + nt * 16 + l16];
    float sSum[2] = {0.f, 0.f}, sSq[2] = {0.f, 0.f};

    const int j0 = lane >> 2;          // scan addressing: chunk within row
    const int of2 = (lane & 3) * 2;    // ushort offset within chunk (2 cols)
    __syncthreads();   // order s_sc/s_sh writes (tid<128) before hoisted reads
    const float ssc0 = s_sc[2 * lane], ssh0 = s_sh[2 * lane];
    const float ssc1 = s_sc[2 * lane + 1], ssh1 = s_sh[2 * lane + 1];

    for (int it = 0; it < RPT; ++it) {
        BAR_ALL;   // (A) X(it) DMA resident; prior epi-store ds_reads done
        if (it + 1 < RPT) stageX(it + 1, (it + 1) & 1);   // in flight until next (A)
        const ushort_t* As = Abuf[it & 1];

        // ---- PASS 1: act whole tile in place + local scan (rows wave*16..+15)
        float pv0[16], pv1[16];
        float base0, base1, lv0 = 0.f, lv1 = 0.f;
        {
            if (it & 3) { base0 = carry[2 * lane]; base1 = carry[2 * lane + 1]; }
            else        { base0 = 0.f; base1 = 0.f; }   // sequence boundary
            ushort_t* Aw = (ushort_t*)Abuf[it & 1];
            #pragma unroll
            for (int i = 0; i < 16; ++i) {
                int r = wave * 16 + i;
                uint_t u = *(const uint_t*)&Aw[r * 128 + ((j0 ^ (r & 15)) * 8) + of2];
                float a0v = fmaxf(fmaf(b2f((ushort_t)(u & 0xffff)), ssc0, ssh0), 0.f);
                float a1v = fmaxf(fmaf(b2f((ushort_t)(u >> 16)), ssc1, ssh1), 0.f);
                *(uint_t*)&Aw[r * 128 + ((j0 ^ (r & 15)) * 8) + of2] = pack2(a0v, a1v);
                lv0 = fmaxf(lv0, a0v);
                lv1 = fmaxf(lv1, a1v);
                pv0[i] = lv0; pv1[i] = lv1;
            }
            gtb[wave * 128 + 2 * lane] = lv0;
            gtb[wave * 128 + 2 * lane + 1] = lv1;
        }
        BAR_LGKM;   // (B1) act'd tile + group totals visible; carry reads done

        float4_t acc[2][2];
        #pragma unroll
        for (int mt = 0; mt < 2; ++mt)
            #pragma unroll
            for (int nt = 0; nt < 2; ++nt) acc[mt][nt] = (float4_t)0.f;

        // ---- kt0: PRE-ACTIVATED fragments; B kt=0 half ----
        #pragma unroll
        for (int kk = 0; kk < 4; ++kk) {
            int j = kk * 4 + quad;
            short8_t a0 = *(const short8_t*)&As[(wm * 32 + l16) * 128 + ((j ^ l16) * 8)];
            short8_t a1 = *(const short8_t*)&As[(wm * 32 + 16 + l16) * 128 + ((j ^ l16) * 8)];
            #pragma unroll
            for (int nt = 0; nt < 2; ++nt) {
                int br = wn * 32 + nt * 16 + l16;
                short8_t bf = *(const short8_t*)&Bs[br * 256 + ((j ^ l16) * 8)];
                acc[0][nt] = __builtin_amdgcn_mfma_f32_16x16x32_bf16(a0, bf, acc[0][nt], 0, 0, 0);
                acc[1][nt] = __builtin_amdgcn_mfma_f32_16x16x32_bf16(a1, bf, acc[1][nt], 0, 0, 0);
            }
        }
        BAR_LGKM;   // (B2) kt0 fragment reads done

        // ---- PASS 2: prefix-combine + write P in place ----
        {
            float o0 = base0, o1 = base1;
            for (int gg = 0; gg < wave; ++gg) {
                o0 = fmaxf(o0, gtb[gg * 128 + 2 * lane]);
                o1 = fmaxf(o1, gtb[gg * 128 + 2 * lane + 1]);
            }
            if (wave == 3) {   // next-tile carry (old-carry reads were pre-B1)
                carry[2 * lane]     = fmaxf(o0, lv0);
                carry[2 * lane + 1] = fmaxf(o1, lv1);
            }
            ushort_t* Aw = (ushort_t*)Abuf[it & 1];
            #pragma unroll
            for (int i = 0; i < 16; ++i) {
                int r = wave * 16 + i;
                *(uint_t*)&Aw[r * 128 + ((j0 ^ (r & 15)) * 8) + of2] =
                    pack2(fmaxf(pv0[i], o0), fmaxf(pv1[i], o1));
            }
        }
        BAR_LGKM;   // (C) P visible

        // ---- kt1: P fragments; B kt=1 half ----
        #pragma unroll
        for (int kk = 0; kk < 4; ++kk) {
            int j = kk * 4 + quad;
            short8_t a0 = *(const short8_t*)&As[(wm * 32 + l16) * 128 + ((j ^ l16) * 8)];
            short8_t a1 = *(const short8_t*)&As[(wm * 32 + 16 + l16) * 128 + ((j ^ l16) * 8)];
            #pragma unroll
            for (int nt = 0; nt < 2; ++nt) {
                int br = wn * 32 + nt * 16 + l16;
                short8_t bf = *(const short8_t*)&Bs[br * 256 + 128 + ((j ^ l16) * 8)];
                acc[0][nt] = __builtin_amdgcn_mfma_f32_16x16x32_bf16(a0, bf, acc[0][nt], 0, 0, 0);
                acc[1][nt] = __builtin_amdgcn_mfma_f32_16x16x32_bf16(a1, bf, acc[1][nt], 0, 0, 0);
            }
        }

        // ---- bias + stats accumulate ----
        #pragma unroll
        for (int mt = 0; mt < 2; ++mt)
            #pragma unroll
            for (int nt = 0; nt < 2; ++nt)
                #pragma unroll
                for (int r = 0; r < 4; ++r) {
                    float v = acc[mt][nt][r] + bvs[nt];
                    acc[mt][nt][r] = v;
                    sSum[nt] += v; sSq[nt] = fmaf(v, v, sSq[nt]);
                }
        if (it == RPT - 1) {
            #pragma unroll
            for (int nt = 0; nt < 2; ++nt) {
                float s = sSum[nt], q = sSq[nt];
                s += __shfl_xor(s, 16); q += __shfl_xor(q, 16);
                s += __shfl_xor(s, 32); q += __shfl_xor(q, 32);
                if (lane < 16) {
                    int colL = wn * 32 + nt * 16 + l16;
                    sred[(wave * 64 + colL) * 2 + 0] = s;
                    sred[(wave * 64 + colL) * 2 + 1] = q;
                }
            }
        }
        BAR_LGKM;   // (D) kt1 reads of Abuf done; sred visible

        // ---- swizzled transpose into Abuf[it&1] (dead after kt1) ----
        char* eb = (char*)Abuf[it & 1];
        #pragma unroll
        for (int mt = 0; mt < 2; ++mt)
            #pragma unroll
            for (int nt = 0; nt < 2; ++nt) {
                int colL = wn * 32 + nt * 16 + l16;
                int bc = colL * 2;
                #pragma unroll
                for (int r = 0; r < 4; ++r) {
                    int row = wm * 32 + mt * 16 + quad * 4 + r;
                    int addr = row * 128 + ((((bc >> 4) ^ (row & 7)) << 4) | (bc & 15));
                    *(ushort_t*)(eb + addr) = f2b(acc[mt][nt][r]);
                }
            }
        if (it == RPT - 1 && tid < 128) {
            int colL = tid & 63, qs = tid >> 6;
            int wb = (colL >> 5) * 2;   // the two waves (wm=0,1) owning this col
            float v = sred[(wb * 64 + colL) * 2 + qs] + sred[((wb + 1) * 64 + colL) * 2 + qs];
            atomicAdd(accumOut + qs * 128 + n0 + colL, v);
        }
        BAR_LGKM;   // (E) epi tile resident

        // ---- coalesced 16 B stores of the 64-col half (128 B per row) ----
        int r0s = row0 + it * 64;
        #pragma unroll
        for (int p = 0; p < 2; ++p) {
            int s = p * 256 + tid;
            int row = s >> 3, gg2 = s & 7;
            uint4 v = *(const uint4*)(eb + row * 128 + ((gg2 ^ (row & 7)) << 4));
            *(uint4*)((char*)(C + (size_t)(r0s + row) * 128 + n0) + gg2 * 16) = v;
        }
    }
}

// ---------------------------------------------------------------------------
// Persistent pipelined MFMA GEMM for K=128 layers: C = act(A)@W + bias.
// MODE==1: act-on-fragments (coeffs from accumIn).
// MODE==2: FUSED act+causal-cummax via 4-wave segmented scan before MFMA.
// Raw barriers: only loop-top drains vmcnt (full-tile DMA prefetch window).
// ---------------------------------------------------------------------------
template<int N, int MODE, int STATS, int RPT, typename CT>
__launch_bounds__(256)
__global__ void mfma_gemm3_k(const ushort_t* __restrict__ A, const ushort_t* __restrict__ WT,
                             const float* __restrict__ bias,
                             const float* __restrict__ g, const float* __restrict__ be,
                             const float* __restrict__ accumIn,
                             CT* __restrict__ C, float* __restrict__ accumOut) {
    constexpr int WN = N / 2;        // cols per wave-column (64 or 32)
    constexpr int NT = WN / 16;      // 4 (N=128) or 2 (N=64)

    __shared__ __attribute__((aligned(16))) ushort_t Bs[N * 128];
    __shared__ __attribute__((aligned(16))) ushort_t Abuf[2][64 * 128];
    __shared__ float sred[STATS ? 4 * N * 2 : 1];
    __shared__ float s_sc[MODE >= 1 ? 128 : 1];
    __shared__ float s_sh[MODE >= 1 ? 128 : 1];
    __shared__ float gtb[MODE == 2 ? 4 * 128 : 1];
    __shared__ float carry[MODE == 2 ? 128 : 1];

    const int tid = threadIdx.x;
    const int lane = tid & 63;
    const int wave = tid >> 6;
    const int wm = wave & 1;
    const int wn = wave >> 1;
    const int quad = lane >> 4;
    const int l16 = lane & 15;
    const int srow = lane >> 4;
    const int sp16 = lane & 15;

    if (MODE >= 1 && tid < 128) {
        float sc, sh;
        bn_coeff(accumIn[tid], accumIn[128 + tid], g[tid], be[tid], sc, sh);
        s_sc[tid] = sc; s_sh[tid] = sh;
    }

    #pragma unroll
    for (int i = 0; i < N / 16; ++i) {
        int t = i * 4 + wave;
        int r = t * 4 + srow;
        int sp = sp16 ^ (r & 15);
        gld_lds16(WT + (size_t)r * 128 + sp * 8, Bs + t * 512);
    }
    {
        int r0 = blockIdx.x * (RPT * 64);
        #pragma unroll
        for (int i = 0; i < 4; ++i) {
            int t = i * 4 + wave;
            int r = t * 4 + srow;
            int sp = sp16 ^ (r & 15);
            gld_lds16(A + (size_t)(r0 + r) * 128 + sp * 8, Abuf[0] + t * 512);
        }
    }

    float bvs[NT];
    #pragma unroll
    for (int nt = 0; nt < NT; ++nt) bvs[nt] = bias[wn * WN + nt * 16 + l16];
    float sSum[STATS ? NT : 1] = {0.f}, sSq[STATS ? NT : 1] = {0.f};

    const int j0 = lane >> 2;
    const int of2 = (lane & 3) * 2;

    for (int it = 0; it < RPT; ++it) {
        BAR_ALL;   // tile DMA resident; prior epi-store ds_reads done

        if (it + 1 < RPT) {
            int r0 = blockIdx.x * (RPT * 64) + (it + 1) * 64;
            #pragma unroll
            for (int i = 0; i < 4; ++i) {
                int t = i * 4 + wave;
                int r = t * 4 + srow;
                int sp = sp16 ^ (r & 15);
                gld_lds16(A + (size_t)(r0 + r) * 128 + sp * 8, Abuf[(it + 1) & 1] + t * 512);
            }
        }

        if constexpr (MODE == 2) {
            // ---- 4-wave segmented scan: pass 1 (local act+cummax) ----
            float pv0[16], pv1[16];
            float base0, base1, lv0 = 0.f, lv1 = 0.f;
            float ssc0 = s_sc[2 * lane], ssh0 = s_sh[2 * lane];
            float ssc1 = s_sc[2 * lane + 1], ssh1 = s_sh[2 * lane + 1];
            {
                if (it & 3) { base0 = carry[2 * lane]; base1 = carry[2 * lane + 1]; }
                else        { base0 = 0.f; base1 = 0.f; }
                ushort_t* Aw = (ushort_t*)Abuf[it & 1];
                #pragma unroll
                for (int i = 0; i < 16; ++i) {
                    int r = wave * 16 + i;
                    uint_t u = *(const uint_t*)&Aw[r * 128 + ((j0 ^ (r & 15)) * 8) + of2];
                    lv0 = fmaxf(lv0, fmaxf(fmaf(b2f((ushort_t)(u & 0xffff)), ssc0, ssh0), 0.f));
                    lv1 = fmaxf(lv1, fmaxf(fmaf(b2f((ushort_t)(u >> 16)), ssc1, ssh1), 0.f));
                    pv0[i] = lv0; pv1[i] = lv1;
                }
                gtb[wave * 128 + 2 * lane] = lv0;
                gtb[wave * 128 + 2 * lane + 1] = lv1;
            }
            BAR_LGKM;   // group totals visible; carry reads done
            {
                float o0 = base0, o1 = base1;
                for (int gg = 0; gg < wave; ++gg) {
                    o0 = fmaxf(o0, gtb[gg * 128 + 2 * lane]);
                    o1 = fmaxf(o1, gtb[gg * 128 + 2 * lane + 1]);
                }
                if (wave == 3) {
                    carry[2 * lane]     = fmaxf(o0, lv0);
                    carry[2 * lane + 1] = fmaxf(o1, lv1);
                }
                ushort_t* Aw = (ushort_t*)Abuf[it & 1];
                #pragma unroll
                for (int i = 0; i < 16; ++i) {
                    int r = wave * 16 + i;
                    *(uint_t*)&Aw[r * 128 + ((j0 ^ (r & 15)) * 8) + of2] =
                        pack2(fmaxf(pv0[i], o0), fmaxf(pv1[i], o1));
                }
            }
            BAR_LGKM;   // P visible to all waves
        }

        const ushort_t* As = Abuf[it & 1];

        float4_t acc[2][NT];
        #pragma unroll
        for (int mt = 0; mt < 2; ++mt)
            #pragma unroll
            for (int nt = 0; nt < NT; ++nt) acc[mt][nt] = (float4_t)0.f;

        #pragma unroll
        for (int kk = 0; kk < 4; ++kk) {
            int j = kk * 4 + quad;
            short8_t a0 = *(const short8_t*)&As[(wm * 32 + l16) * 128 + ((j ^ l16) * 8)];
            short8_t a1 = *(const short8_t*)&As[(wm * 32 + 16 + l16) * 128 + ((j ^ l16) * 8)];
            if (MODE == 1) {
                int kb = kk * 32 + quad * 8;
                float4 c0 = *(const float4*)&s_sc[kb], c1 = *(const float4*)&s_sc[kb + 4];
                float4 h0 = *(const float4*)&s_sh[kb], h1 = *(const float4*)&s_sh[kb + 4];
                #pragma unroll
                for (int z = 0; z < 2; ++z) {
                    ushort_t u[8];
                    *(short8_t*)u = z ? a1 : a0;
                    uint_t w[4];
                    w[0] = pack2(fmaxf(fmaf(b2f(u[0]), c0.x, h0.x), 0.f),
                                 fmaxf(fmaf(b2f(u[1]), c0.y, h0.y), 0.f));
                    w[1] = pack2(fmaxf(fmaf(b2f(u[2]), c0.z, h0.z), 0.f),
                                 fmaxf(fmaf(b2f(u[3]), c0.w, h0.w), 0.f));
                    w[2] = pack2(fmaxf(fmaf(b2f(u[4]), c1.x, h1.x), 0.f),
                                 fmaxf(fmaf(b2f(u[5]), c1.y, h1.y), 0.f));
                    w[3] = pack2(fmaxf(fmaf(b2f(u[6]), c1.z, h1.z), 0.f),
                                 fmaxf(fmaf(b2f(u[7]), c1.w, h1.w), 0.f));
                    short8_t rr;
                    *(uint4*)&rr = *(const uint4*)w;
                    if (z) a1 = rr; else a0 = rr;
                }
            }
            #pragma unroll
            for (int nt = 0; nt < NT; ++nt) {
                short8_t bf = *(const short8_t*)&Bs[(wn * WN + nt * 16 + l16) * 128 + ((j ^ l16) * 8)];
                acc[0][nt] = __builtin_amdgcn_mfma_f32_16x16x32_bf16(a0, bf, acc[0][nt], 0, 0, 0);
                acc[1][nt] = __builtin_amdgcn_mfma_f32_16x16x32_bf16(a1, bf, acc[1][nt], 0, 0, 0);
            }
        }

        #pragma unroll
        for (int mt = 0; mt < 2; ++mt)
            #pragma unroll
            for (int nt = 0; nt < NT; ++nt)
                #pragma unroll
                for (int r = 0; r < 4; ++r) {
                    float v = acc[mt][nt][r] + bvs[nt];
                    acc[mt][nt][r] = v;
                    if (STATS) { sSum[nt] += v; sSq[nt] = fmaf(v, v, sSq[nt]); }
                }
        if (STATS && it == RPT - 1) {
            #pragma unroll
            for (int nt = 0; nt < NT; ++nt) {
                float s = sSum[nt], q = sSq[nt];
                s += __shfl_xor(s, 16); q += __shfl_xor(q, 16);
                s += __shfl_xor(s, 32); q += __shfl_xor(q, 32);
                if (lane < 16) {
                    int col = wn * WN + nt * 16 + l16;
                    sred[(wave * N + col) * 2 + 0] = s;
                    sred[(wave * N + col) * 2 + 1] = q;
                }
            }
        }
        BAR_LGKM;   // MFMA frag reads done; sred visible

        char* eb = (char*)Abuf[it & 1];
        #pragma unroll
        for (int mt = 0; mt < 2; ++mt)
            #pragma unroll
            for (int nt = 0; nt < NT; ++nt) {
                int col = wn * WN + nt * 16 + l16;
                int bc = col * (int)sizeof(CT);
                #pragma unroll
                for (int r = 0; r < 4; ++r) {
                    int row = wm * 32 + mt * 16 + quad * 4 + r;
                    int addr = row * 256 + ((((bc >> 4) ^ (row & 15)) << 4) | (bc & 15));
                    if constexpr (sizeof(CT) == 4) *(float*)(eb + addr) = acc[mt][nt][r];
                    else                           *(ushort_t*)(eb + addr) = f2b(acc[mt][nt][r]);
                }
            }
        if (STATS && it == RPT - 1) {
            int col = tid & (N - 1), qs = tid / N;
            int wb = (col / WN) * 2;
            float v = sred[(wb * N + col) * 2 + qs] + sred[((wb + 1) * N + col) * 2 + qs];
            atomicAdd(accumOut + qs * 128 + col, v);
        }
        BAR_LGKM;   // epi tile resident

        int r0 = blockIdx.x * (RPT * 64) + it * 64;
        #pragma unroll
        for (int p = 0; p < 4; ++p) {
            int s = p * 256 + tid;
            int row = s >> 4, gg2 = s & 15;
            uint4 v = *(const uint4*)(eb + row * 256 + ((gg2 ^ (row & 15)) << 4));
            *(uint4*)((char*)(C + (size_t)(r0 + row) * N) + gg2 * 16) = v;
        }
    }
}

// ---------------------------------------------------------------------------
// fp32 vector GEMM (layer 0: K=32, fp32 input), grid-strided over RPT row
// tiles per block. Weights staged ONCE; A-tile async-stage split (issue loads
// early, ds_write late). Stats in registers across tiles -> one LDS reduce +
// 256 atomics per block (512 blocks -> 131K atomics, proven-safe count).
// ---------------------------------------------------------------------------
template<int K, int N, int RPT>
__launch_bounds__(256)
__global__ void gemm_f32_k(const float* __restrict__ A, const float* __restrict__ W,
                           const float* __restrict__ bias, ushort_t* __restrict__ C,
                           float* __restrict__ accum) {
    constexpr int TX = N / 4;        // 32
    constexpr int TY = 256 / TX;     // 8
    constexpr int RM = TILE_M / TY;  // 8

    __shared__ float As[2][TILE_M][BK + 1];
    __shared__ float Ws[BK][N];
    __shared__ float redst[2][TY][N];

    const int tid = threadIdx.x;
    const int tx = tid % TX;
    const int ty = tid / TX;
    const int row0 = blockIdx.x * (RPT * TILE_M);
    const int arow = tid >> 2;
    const int acol = (tid & 3) * 8;

    // ---- stage weights once (K=32 -> whole K fits one tile) ----
    #pragma unroll
    for (int i = 0; i < (BK * N) / 256; ++i) {
        int e = i * 256 + tid;
        Ws[e / N][e % N] = W[(size_t)(e / N) * N + e % N];
    }
    // ---- preload tile 0 A ----
    {
        const float4* p = (const float4*)&A[(size_t)(row0 + arow) * K + acol];
        float4 x0 = p[0], x1 = p[1];
        As[0][arow][acol + 0] = x0.x; As[0][arow][acol + 1] = x0.y;
        As[0][arow][acol + 2] = x0.z; As[0][arow][acol + 3] = x0.w;
        As[0][arow][acol + 4] = x1.x; As[0][arow][acol + 5] = x1.y;
        As[0][arow][acol + 6] = x1.z; As[0][arow][acol + 7] = x1.w;
    }

    float4 bv = *(const float4*)&bias[tx * 4];
    float s[4] = {0, 0, 0, 0}, q[4] = {0, 0, 0, 0};

    for (int it = 0; it < RPT; ++it) {
        __syncthreads();   // As[it&1] (and Ws on it=0) resident
        // issue next tile's loads EARLY (latency hides under FMA loop)
        float4 nx0, nx1;
        if (it + 1 < RPT) {
            const float4* p = (const float4*)&A[(size_t)(row0 + (it + 1) * TILE_M + arow) * K + acol];
            nx0 = p[0]; nx1 = p[1];
        }

        float acc[RM][4];
        #pragma unroll
        for (int r = 0; r < RM; ++r)
            #pragma unroll
            for (int c = 0; c < 4; ++c) acc[r][c] = 0.f;
        #pragma unroll
        for (int kk = 0; kk < BK; ++kk) {
            float4 wv = *(const float4*)&Ws[kk][tx * 4];
            #pragma unroll
            for (int r = 0; r < RM; ++r) {
                float a = As[it & 1][ty * RM + r][kk];
                acc[r][0] = fmaf(a, wv.x, acc[r][0]);
                acc[r][1] = fmaf(a, wv.y, acc[r][1]);
                acc[r][2] = fmaf(a, wv.z, acc[r][2]);
                acc[r][3] = fmaf(a, wv.w, acc[r][3]);
            }
        }

        // bias + stats + coalesced bf16 store for this tile
        #pragma unroll
        for (int r = 0; r < RM; ++r) {
            float o[4];
            o[0] = acc[r][0] + bv.x; o[1] = acc[r][1] + bv.y;
            o[2] = acc[r][2] + bv.z; o[3] = acc[r][3] + bv.w;
            #pragma unroll
            for (int c = 0; c < 4; ++c) { s[c] += o[c]; q[c] = fmaf(o[c], o[c], q[c]); }
            size_t off = (size_t)(row0 + it * TILE_M + ty * RM + r) * N + tx * 4;
            uint2 ov;
            ov.x = pack2(o[0], o[1]);
            ov.y = pack2(o[2], o[3]);
            *(uint2*)&C[off] = ov;
        }

        // ds_write the prefetched tile LATE (vmcnt wait lands after compute)
        if (it + 1 < RPT) {
            int b = (it + 1) & 1;
            As[b][arow][acol + 0] = nx0.x; As[b][arow][acol + 1] = nx0.y;
            As[b][arow][acol + 2] = nx0.z; As[b][arow][acol + 3] = nx0.w;
            As[b][arow][acol + 4] = nx1.x; As[b][arow][acol + 5] = nx1.y;
            As[b][arow][acol + 6] = nx1.z; As[b][arow][acol + 7] = nx1.w;
        }
    }

    __syncthreads();   // As reads done; redst region free
    #pragma unroll
    for (int c = 0; c < 4; ++c) {
        redst[0][ty][tx * 4 + c] = s[c];
        redst[1][ty][tx * 4 + c] = q[c];
    }
    __syncthreads();
    {
        int col = tid & (N - 1), qs = tid / N;
        float v = 0.f;
        #pragma unroll
        for (int t = 0; t < TY; ++t) v += redst[qs][t][col];
        atomicAdd(accum + qs * 128 + col, v);
    }
}

// All four weight transposes in one launch: fp32 W[K][N] -> bf16 WT[N][K]
__global__ void transpose_all_k(const float* __restrict__ W1, const float* __restrict__ W2,
                                const float* __restrict__ W3, const float* __restrict__ W4,
                                ushort_t* __restrict__ wt1, ushort_t* __restrict__ wt2,
                                ushort_t* __restrict__ wt3, ushort_t* __restrict__ wt4) {
    int idx = blockIdx.x * 256 + threadIdx.x;
    if (idx < 32768) {                       // W1: 256 x 128
        int k = idx >> 7, n = idx & 127;
        wt1[(size_t)n * 256 + k] = f2b(W1[idx]);
    } else if (idx < 49152) {                // W2: 128 x 128
        int i = idx - 32768;
        int k = i >> 7, n = i & 127;
        wt2[(size_t)n * 128 + k] = f2b(W2[i]);
    } else if (idx < 65536) {                // W3: 128 x 128
        int i = idx - 49152;
        int k = i >> 7, n = i & 127;
        wt3[(size_t)n * 128 + k] = f2b(W3[i]);
    } else if (idx < 73728) {                // W4: 128 x 64
        int i = idx - 65536;
        int k = i >> 6, n = i & 63;
        wt4[(size_t)n * 128 + k] = f2b(W4[i]);
    }
}

extern "C" void kernel_launch(void* const* d_in, const int* in_sizes, int n_in,
                              void* d_out, int out_size, void* d_ws, size_t ws_size,
                              hipStream_t stream) {
    const float* poly = (const float*)d_in[0];
    const float* W0 = (const float*)d_in[1];
    const float* b0 = (const float*)d_in[2];
    const float* g0 = (const float*)d_in[3];
    const float* be0 = (const float*)d_in[4];
    const float* W1 = (const float*)d_in[5];
    const float* b1 = (const float*)d_in[6];
    const float* g1 = (const float*)d_in[7];
    const float* be1 = (const float*)d_in[8];
    const float* W2 = (const float*)d_in[9];
    const float* b2 = (const float*)d_in[10];
    const float* g2 = (const float*)d_in[11];
    const float* be2 = (const float*)d_in[12];
    const float* W3 = (const float*)d_in[13];
    const float* b3 = (const float*)d_in[14];
    const float* g3 = (const float*)d_in[15];
    const float* be3 = (const float*)d_in[16];
    const float* W4 = (const float*)d_in[17];
    const float* b4 = (const float*)d_in[18];
    float* out = (float*)d_out;

    float* st = (float*)d_ws;
    float* accum = st + 1048576;            // 4 layers x 256 floats
    ushort_t* wt1 = (ushort_t*)((char*)d_ws + 4263936);         // 128 x 256
    ushort_t* wt2 = wt1 + 128 * 256;                            // 128 x 128
    ushort_t* wt3 = wt2 + 128 * 128;                            // 128 x 128
    ushort_t* wt4 = wt3 + 128 * 128;                            // 64 x 128
    ushort_t* h0 = (ushort_t*)((char*)d_ws + 4263936 + 147456);
    ushort_t* y1 = (ushort_t*)out;   // d_out doubles as y1 scratch (M*128 bf16
                                     // == out_size bytes); overwritten by L4.

    const int GP = M_ROWS / (64 * 8);   // 512 (persistent kernels, RPT=8)

    // zero all stat accumulators (4 layers x 256 floats) before any atomics
    hipMemsetAsync(accum, 0, 1024 * sizeof(float), stream);

    // Layer 0 (fp32 precision): y0 = poly @ W0 + b0 -> h0 (raw bf16) + stats(accum)
    gemm_f32_k<32, 128, 8><<<GP, 256, 0, stream>>>(poly, W0, b0, h0, accum);
    transpose_all_k<<<288, 256, 0, stream>>>(W1, W2, W3, W4, wt1, wt2, wt3, wt4);

    // Layer 1 (FUSED scan): y1 = [bnrelu0(y0), cummax(bnrelu0(y0))] @ W1 + b1
    //   -> d_out scratch; BN0 finalize folded in; stats -> accum+256
    gemm1s_k<8><<<2 * GP, 256, 0, stream>>>(h0, wt1, b1, g0, be0, accum,
                                            y1, accum + 256);

    // Layer 2: y2 = bnrelu1(y1) @ W2 + b2 : d_out -> h0; stats -> accum+512
    mfma_gemm3_k<128, 1, 1, 8, ushort_t><<<GP, 256, 0, stream>>>(
        y1, wt2, b2, g1, be1, accum + 256, h0, accum + 512);

    // Layer 3 (FUSED scan): y3 = cummax(bnrelu2(y2)) @ W3 + b3 -> h0 in place;
    //   BN2 finalize folded in; stats -> accum+768
    mfma_gemm3_k<128, 2, 1, 8, ushort_t><<<GP, 256, 0, stream>>>(
        h0, wt3, b3, g2, be2, accum + 512, h0, accum + 768);

    // Layer 4: out = bnrelu3(y3) @ W4 + b4 -> d_out (fp32; overwrites y1 scratch)
    mfma_gemm3_k<64, 1, 0, 8, float><<<GP, 256, 0, stream>>>(
        h0, wt4, b4, g3, be3, accum + 768, out, nullptr);
}

// Round 14
// 310.510 us; speedup vs baseline: 1.0245x; 1.0245x over previous
//
#include <hip/hip_runtime.h>
#include <hip/hip_bf16.h>

// Problem constants (fixed by setup_inputs)
#define M_ROWS 262144   // B*A*T = 16*64*256
#define TILE_M 64
#define BK 32
#define INVM (1.0f / 262144.0f)

typedef unsigned short ushort_t;
typedef unsigned int uint_t;
typedef __attribute__((ext_vector_type(8))) short short8_t;   // 8 bf16 = 4 VGPRs
typedef __attribute__((ext_vector_type(4))) float float4_t;   // MFMA acc

// bf16 (stored as ushort) <-> fp32 helpers. Load is exact; store is RNE.
__device__ __forceinline__ float b2f(ushort_t u) {
    union { uint_t i; float f; } c; c.i = ((uint_t)u) << 16; return c.f;
}
__device__ __forceinline__ ushort_t f2b(float f) {
    union { float f; uint_t i; } c; c.f = f;
    uint_t u = c.i;
    return (ushort_t)((u + 0x7fffu + ((u >> 16) & 1u)) >> 16);
}
// packed 2xfp32 -> 2xbf16 (v_cvt_pk_bf16_f32 on gfx950, RNE)
__device__ __forceinline__ uint_t pack2(float a, float b) {
    union { __hip_bfloat162 h; uint_t u; } c;
    c.h = __float22bfloat162_rn(make_float2(a, b));
    return c.u;
}

// async global->LDS DMA, 16 B per lane; data lands at ldsbase + lane*16
__device__ __forceinline__ void gld_lds16(const ushort_t* g, ushort_t* l) {
    __builtin_amdgcn_global_load_lds((const __attribute__((address_space(1))) void*)g,
                                     (__attribute__((address_space(3))) void*)l, 16, 0, 0);
}

// BN finalize arithmetic (shared by all consumers): from accumulated sum/sumsq.
__device__ __forceinline__ void bn_coeff(float s, float q, float g, float be,
                                         float& sc, float& sh) {
    float mean = s * INVM;
    float var = q * INVM - mean * mean;
    sc = g * rsqrtf(var + 1e-5f);
    sh = fmaf(-mean, sc, be);
}

// ---------------------------------------------------------------------------
// Layer-1 N-SPLIT pipelined GEMM with FUSED causal-cummax:
//   C = [bnrelu0(X), cummax(bnrelu0(X))] @ W1 + b1  (K=256), X read ONCE.
// Grid = 1024 blocks; XCD-aware swizzle (T1): logical id lg = (bid&7)*128 +
// (bid>>3) puts logical-contiguous blocks on ONE XCD, so the half-pair
// (2t, 2t+1) — which reads the SAME 64 X-rows — shares that XCD's L2
// (default round-robin put pairs on different XCDs -> LLC round-trips).
// Per tile: PASS1 = act whole tile IN PLACE (once per element) + local 16-row
// scan into regs + group totals -> kt0 MFMA reads PRE-ACTIVATED frags ->
// PASS2 = prefix-combine + write P in place (+carry) -> kt1 MFMA on P frags.
// Prefetch DMA issued at loop-top. BN coeffs from accumIn (finalize folded);
// stats atomicAdd into accumOut.
// ---------------------------------------------------------------------------
template<int RPT>
__launch_bounds__(256)
__global__ void gemm1s_k(const ushort_t* __restrict__ X,
                         const ushort_t* __restrict__ WT, const float* __restrict__ bias,
                         const float* __restrict__ g, const float* __restrict__ be,
                         const float* __restrict__ accumIn,
                         ushort_t* __restrict__ C, float* __restrict__ accumOut) {
    __shared__ __attribute__((aligned(16))) ushort_t Bs[64 * 256];       // 32 KB
    __shared__ __attribute__((aligned(16))) ushort_t Abuf[2][64 * 128];  // 2x16 KB
    __shared__ float sred[4 * 64 * 2];
    __shared__ float s_sc[128], s_sh[128];
    __shared__ float gtb[4 * 128];    // scan group totals
    __shared__ float carry[128];      // inter-tile scan carry

    const int tid = threadIdx.x;
    const int lane = tid & 63;
    const int wave = tid >> 6;
    const int wm = wave & 1, wn = wave >> 1;
    const int quad = lane >> 4, l16 = lane & 15;
    const int srow = lane >> 4, sp16 = lane & 15;   // A staging
    const int brow = lane >> 5, bs32 = lane & 31;   // B staging (512 B rows)
    const int lg = (blockIdx.x & 7) * 128 + (blockIdx.x >> 3);  // XCD swizzle
    const int tileId = lg >> 1;
    const int n0 = (lg & 1) * 64;                   // column-half offset
    const int row0 = tileId * (RPT * 64);

    if (tid < 128) {
        float sc, sh;
        bn_coeff(accumIn[tid], accumIn[128 + tid], g[tid], be[tid], sc, sh);
        s_sc[tid] = sc; s_sh[tid] = sh;
    }

    // ---- stage B half (rows n0..n0+63 of WT, 512 B each): 32 chunks x 1 KB ----
    #pragma unroll
    for (int i = 0; i < 8; ++i) {
        int t = i * 4 + wave;
        int r = t * 2 + brow;                        // local B row 0..63
        int sp = (bs32 & 16) | ((bs32 ^ r) & 15);    // half-preserving XOR swizzle
        gld_lds16(WT + (size_t)(n0 + r) * 256 + sp * 8, Bs + t * 512);
    }

    auto stageX = [&](int it, int buf) {
        int r0 = row0 + it * 64;
        #pragma unroll
        for (int i = 0; i < 4; ++i) {
            int t = i * 4 + wave;
            int r = t * 4 + srow;
            int sp = sp16 ^ (r & 15);
            gld_lds16(X + (size_t)(r0 + r) * 128 + sp * 8, Abuf[buf] + t * 512);
        }
    };
    stageX(0, 0);

    float bvs[2];
    #pragma unroll
    for (int nt = 0; nt < 2; ++nt) bvs[nt] = bias[n0 + wn * 32 + nt * 16 + l16];
    float sSum[2] = {0.f, 0.f}, sSq[2] = {0.f, 0.f};

    const int j0 = lane >> 2;          // scan addressing: chunk within row
    const int of2 = (lane & 3) * 2;    // ushort offset within chunk (2 cols)
    __syncthreads();   // order s_sc/s_sh writes (tid<128) before hoisted reads
    const float ssc0 = s_sc[2 * lane], ssh0 = s_sh[2 * lane];
    const float ssc1 = s_sc[2 * lane + 1], ssh1 = s_sh[2 * lane + 1];

    for (int it = 0; it < RPT; ++it) {
        __syncthreads();   // (A) X(it) resident; prior epi-store reads done
        if (it + 1 < RPT) stageX(it + 1, (it + 1) & 1);   // DMA overlaps whole tile
        const ushort_t* As = Abuf[it & 1];

        // ---- PASS 1: act whole tile in place + local scan (rows wave*16..+15)
        float pv0[16], pv1[16];
        float base0, base1, lv0 = 0.f, lv1 = 0.f;
        {
            if (it & 3) { base0 = carry[2 * lane]; base1 = carry[2 * lane + 1]; }
            else        { base0 = 0.f; base1 = 0.f; }   // sequence boundary
            ushort_t* Aw = (ushort_t*)Abuf[it & 1];
            #pragma unroll
            for (int i = 0; i < 16; ++i) {
                int r = wave * 16 + i;
                uint_t u = *(const uint_t*)&Aw[r * 128 + ((j0 ^ (r & 15)) * 8) + of2];
                float a0v = fmaxf(fmaf(b2f((ushort_t)(u & 0xffff)), ssc0, ssh0), 0.f);
                float a1v = fmaxf(fmaf(b2f((ushort_t)(u >> 16)), ssc1, ssh1), 0.f);
                *(uint_t*)&Aw[r * 128 + ((j0 ^ (r & 15)) * 8) + of2] = pack2(a0v, a1v);
                lv0 = fmaxf(lv0, a0v);
                lv1 = fmaxf(lv1, a1v);
                pv0[i] = lv0; pv1[i] = lv1;
            }
            gtb[wave * 128 + 2 * lane] = lv0;
            gtb[wave * 128 + 2 * lane + 1] = lv1;
        }
        __syncthreads();   // (B1) act'd tile + group totals visible; carry reads done

        float4_t acc[2][2];
        #pragma unroll
        for (int mt = 0; mt < 2; ++mt)
            #pragma unroll
            for (int nt = 0; nt < 2; ++nt) acc[mt][nt] = (float4_t)0.f;

        // ---- kt0: PRE-ACTIVATED fragments; B kt=0 half (no act block) ----
        #pragma unroll
        for (int kk = 0; kk < 4; ++kk) {
            int j = kk * 4 + quad;
            short8_t a0 = *(const short8_t*)&As[(wm * 32 + l16) * 128 + ((j ^ l16) * 8)];
            short8_t a1 = *(const short8_t*)&As[(wm * 32 + 16 + l16) * 128 + ((j ^ l16) * 8)];
            #pragma unroll
            for (int nt = 0; nt < 2; ++nt) {
                int br = wn * 32 + nt * 16 + l16;
                short8_t bf = *(const short8_t*)&Bs[br * 256 + ((j ^ l16) * 8)];
                acc[0][nt] = __builtin_amdgcn_mfma_f32_16x16x32_bf16(a0, bf, acc[0][nt], 0, 0, 0);
                acc[1][nt] = __builtin_amdgcn_mfma_f32_16x16x32_bf16(a1, bf, acc[1][nt], 0, 0, 0);
            }
        }
        __syncthreads();   // (B2) kt0 fragment reads done

        // ---- PASS 2: prefix-combine + write P in place ----
        {
            float o0 = base0, o1 = base1;
            for (int gg = 0; gg < wave; ++gg) {
                o0 = fmaxf(o0, gtb[gg * 128 + 2 * lane]);
                o1 = fmaxf(o1, gtb[gg * 128 + 2 * lane + 1]);
            }
            if (wave == 3) {   // next-tile carry (old-carry reads were pre-B1)
                carry[2 * lane]     = fmaxf(o0, lv0);
                carry[2 * lane + 1] = fmaxf(o1, lv1);
            }
            ushort_t* Aw = (ushort_t*)Abuf[it & 1];
            #pragma unroll
            for (int i = 0; i < 16; ++i) {
                int r = wave * 16 + i;
                *(uint_t*)&Aw[r * 128 + ((j0 ^ (r & 15)) * 8) + of2] =
                    pack2(fmaxf(pv0[i], o0), fmaxf(pv1[i], o1));
            }
        }
        __syncthreads();   // (C) P visible

        // ---- kt1: P fragments; B kt=1 half ----
        #pragma unroll
        for (int kk = 0; kk < 4; ++kk) {
            int j = kk * 4 + quad;
            short8_t a0 = *(const short8_t*)&As[(wm * 32 + l16) * 128 + ((j ^ l16) * 8)];
            short8_t a1 = *(const short8_t*)&As[(wm * 32 + 16 + l16) * 128 + ((j ^ l16) * 8)];
            #pragma unroll
            for (int nt = 0; nt < 2; ++nt) {
                int br = wn * 32 + nt * 16 + l16;
                short8_t bf = *(const short8_t*)&Bs[br * 256 + 128 + ((j ^ l16) * 8)];
                acc[0][nt] = __builtin_amdgcn_mfma_f32_16x16x32_bf16(a0, bf, acc[0][nt], 0, 0, 0);
                acc[1][nt] = __builtin_amdgcn_mfma_f32_16x16x32_bf16(a1, bf, acc[1][nt], 0, 0, 0);
            }
        }

        // ---- bias + stats accumulate ----
        #pragma unroll
        for (int mt = 0; mt < 2; ++mt)
            #pragma unroll
            for (int nt = 0; nt < 2; ++nt)
                #pragma unroll
                for (int r = 0; r < 4; ++r) {
                    float v = acc[mt][nt][r] + bvs[nt];
                    acc[mt][nt][r] = v;
                    sSum[nt] += v; sSq[nt] = fmaf(v, v, sSq[nt]);
                }
        if (it == RPT - 1) {
            #pragma unroll
            for (int nt = 0; nt < 2; ++nt) {
                float s = sSum[nt], q = sSq[nt];
                s += __shfl_xor(s, 16); q += __shfl_xor(q, 16);
                s += __shfl_xor(s, 32); q += __shfl_xor(q, 32);
                if (lane < 16) {
                    int colL = wn * 32 + nt * 16 + l16;
                    sred[(wave * 64 + colL) * 2 + 0] = s;
                    sred[(wave * 64 + colL) * 2 + 1] = q;
                }
            }
        }
        __syncthreads();   // (D) kt1 reads of Abuf done; sred visible

        // ---- swizzled transpose into Abuf[it&1] (dead after kt1) ----
        char* eb = (char*)Abuf[it & 1];
        #pragma unroll
        for (int mt = 0; mt < 2; ++mt)
            #pragma unroll
            for (int nt = 0; nt < 2; ++nt) {
                int colL = wn * 32 + nt * 16 + l16;
                int bc = colL * 2;
                #pragma unroll
                for (int r = 0; r < 4; ++r) {
                    int row = wm * 32 + mt * 16 + quad * 4 + r;
                    int addr = row * 128 + ((((bc >> 4) ^ (row & 7)) << 4) | (bc & 15));
                    *(ushort_t*)(eb + addr) = f2b(acc[mt][nt][r]);
                }
            }
        if (it == RPT - 1 && tid < 128) {
            int colL = tid & 63, qs = tid >> 6;
            int wb = (colL >> 5) * 2;   // the two waves (wm=0,1) owning this col
            float v = sred[(wb * 64 + colL) * 2 + qs] + sred[((wb + 1) * 64 + colL) * 2 + qs];
            atomicAdd(accumOut + qs * 128 + n0 + colL, v);
        }
        __syncthreads();   // (E) epi tile resident

        // ---- coalesced 16 B stores of the 64-col half (128 B per row) ----
        int r0s = row0 + it * 64;
        #pragma unroll
        for (int p = 0; p < 2; ++p) {
            int s = p * 256 + tid;
            int row = s >> 3, gg2 = s & 7;
            uint4 v = *(const uint4*)(eb + row * 128 + ((gg2 ^ (row & 7)) << 4));
            *(uint4*)((char*)(C + (size_t)(r0s + row) * 128 + n0) + gg2 * 16) = v;
        }
    }
}

// ---------------------------------------------------------------------------
// Persistent pipelined MFMA GEMM for K=128 layers: C = act(A)@W + bias.
// MODE==1: act-on-fragments (coeffs from accumIn).
// MODE==2: FUSED act+causal-cummax via 4-wave segmented scan before MFMA
//          (local 16-row chains in regs + group-total prefix + carry).
// ---------------------------------------------------------------------------
template<int N, int MODE, int STATS, int RPT, typename CT>
__launch_bounds__(256)
__global__ void mfma_gemm3_k(const ushort_t* __restrict__ A, const ushort_t* __restrict__ WT,
                             const float* __restrict__ bias,
                             const float* __restrict__ g, const float* __restrict__ be,
                             const float* __restrict__ accumIn,
                             CT* __restrict__ C, float* __restrict__ accumOut) {
    constexpr int WN = N / 2;        // cols per wave-column (64 or 32)
    constexpr int NT = WN / 16;      // 4 (N=128) or 2 (N=64)

    __shared__ __attribute__((aligned(16))) ushort_t Bs[N * 128];
    __shared__ __attribute__((aligned(16))) ushort_t Abuf[2][64 * 128];
    __shared__ float sred[STATS ? 4 * N * 2 : 1];
    __shared__ float s_sc[MODE >= 1 ? 128 : 1];
    __shared__ float s_sh[MODE >= 1 ? 128 : 1];
    __shared__ float gtb[MODE == 2 ? 4 * 128 : 1];
    __shared__ float carry[MODE == 2 ? 128 : 1];

    const int tid = threadIdx.x;
    const int lane = tid & 63;
    const int wave = tid >> 6;
    const int wm = wave & 1;
    const int wn = wave >> 1;
    const int quad = lane >> 4;
    const int l16 = lane & 15;
    const int srow = lane >> 4;
    const int sp16 = lane & 15;

    if (MODE >= 1 && tid < 128) {
        float sc, sh;
        bn_coeff(accumIn[tid], accumIn[128 + tid], g[tid], be[tid], sc, sh);
        s_sc[tid] = sc; s_sh[tid] = sh;
    }

    #pragma unroll
    for (int i = 0; i < N / 16; ++i) {
        int t = i * 4 + wave;
        int r = t * 4 + srow;
        int sp = sp16 ^ (r & 15);
        gld_lds16(WT + (size_t)r * 128 + sp * 8, Bs + t * 512);
    }
    {
        int r0 = blockIdx.x * (RPT * 64);
        #pragma unroll
        for (int i = 0; i < 4; ++i) {
            int t = i * 4 + wave;
            int r = t * 4 + srow;
            int sp = sp16 ^ (r & 15);
            gld_lds16(A + (size_t)(r0 + r) * 128 + sp * 8, Abuf[0] + t * 512);
        }
    }

    float bvs[NT];
    #pragma unroll
    for (int nt = 0; nt < NT; ++nt) bvs[nt] = bias[wn * WN + nt * 16 + l16];
    float sSum[STATS ? NT : 1] = {0.f}, sSq[STATS ? NT : 1] = {0.f};

    const int j0 = lane >> 2;
    const int of2 = (lane & 3) * 2;

    for (int it = 0; it < RPT; ++it) {
        __syncthreads();   // tile resident; prior epi-store reads done

        if (it + 1 < RPT) {
            int r0 = blockIdx.x * (RPT * 64) + (it + 1) * 64;
            #pragma unroll
            for (int i = 0; i < 4; ++i) {
                int t = i * 4 + wave;
                int r = t * 4 + srow;
                int sp = sp16 ^ (r & 15);
                gld_lds16(A + (size_t)(r0 + r) * 128 + sp * 8, Abuf[(it + 1) & 1] + t * 512);
            }
        }

        if constexpr (MODE == 2) {
            // ---- 4-wave segmented scan: pass 1 (local act+cummax) ----
            float pv0[16], pv1[16];
            float base0, base1, lv0 = 0.f, lv1 = 0.f;
            float ssc0 = s_sc[2 * lane], ssh0 = s_sh[2 * lane];
            float ssc1 = s_sc[2 * lane + 1], ssh1 = s_sh[2 * lane + 1];
            {
                if (it & 3) { base0 = carry[2 * lane]; base1 = carry[2 * lane + 1]; }
                else        { base0 = 0.f; base1 = 0.f; }
                ushort_t* Aw = (ushort_t*)Abuf[it & 1];
                #pragma unroll
                for (int i = 0; i < 16; ++i) {
                    int r = wave * 16 + i;
                    uint_t u = *(const uint_t*)&Aw[r * 128 + ((j0 ^ (r & 15)) * 8) + of2];
                    lv0 = fmaxf(lv0, fmaxf(fmaf(b2f((ushort_t)(u & 0xffff)), ssc0, ssh0), 0.f));
                    lv1 = fmaxf(lv1, fmaxf(fmaf(b2f((ushort_t)(u >> 16)), ssc1, ssh1), 0.f));
                    pv0[i] = lv0; pv1[i] = lv1;
                }
                gtb[wave * 128 + 2 * lane] = lv0;
                gtb[wave * 128 + 2 * lane + 1] = lv1;
            }
            __syncthreads();   // group totals visible; carry reads done
            {
                float o0 = base0, o1 = base1;
                for (int gg = 0; gg < wave; ++gg) {
                    o0 = fmaxf(o0, gtb[gg * 128 + 2 * lane]);
                    o1 = fmaxf(o1, gtb[gg * 128 + 2 * lane + 1]);
                }
                if (wave == 3) {
                    carry[2 * lane]     = fmaxf(o0, lv0);
                    carry[2 * lane + 1] = fmaxf(o1, lv1);
                }
                ushort_t* Aw = (ushort_t*)Abuf[it & 1];
                #pragma unroll
                for (int i = 0; i < 16; ++i) {
                    int r = wave * 16 + i;
                    *(uint_t*)&Aw[r * 128 + ((j0 ^ (r & 15)) * 8) + of2] =
                        pack2(fmaxf(pv0[i], o0), fmaxf(pv1[i], o1));
                }
            }
            __syncthreads();   // P visible to all waves
        }

        const ushort_t* As = Abuf[it & 1];

        float4_t acc[2][NT];
        #pragma unroll
        for (int mt = 0; mt < 2; ++mt)
            #pragma unroll
            for (int nt = 0; nt < NT; ++nt) acc[mt][nt] = (float4_t)0.f;

        #pragma unroll
        for (int kk = 0; kk < 4; ++kk) {
            int j = kk * 4 + quad;
            short8_t a0 = *(const short8_t*)&As[(wm * 32 + l16) * 128 + ((j ^ l16) * 8)];
            short8_t a1 = *(const short8_t*)&As[(wm * 32 + 16 + l16) * 128 + ((j ^ l16) * 8)];
            if (MODE == 1) {
                int kb = kk * 32 + quad * 8;
                float4 c0 = *(const float4*)&s_sc[kb], c1 = *(const float4*)&s_sc[kb + 4];
                float4 h0 = *(const float4*)&s_sh[kb], h1 = *(const float4*)&s_sh[kb + 4];
                #pragma unroll
                for (int z = 0; z < 2; ++z) {
                    ushort_t u[8];
                    *(short8_t*)u = z ? a1 : a0;
                    uint_t w[4];
                    w[0] = pack2(fmaxf(fmaf(b2f(u[0]), c0.x, h0.x), 0.f),
                                 fmaxf(fmaf(b2f(u[1]), c0.y, h0.y), 0.f));
                    w[1] = pack2(fmaxf(fmaf(b2f(u[2]), c0.z, h0.z), 0.f),
                                 fmaxf(fmaf(b2f(u[3]), c0.w, h0.w), 0.f));
                    w[2] = pack2(fmaxf(fmaf(b2f(u[4]), c1.x, h1.x), 0.f),
                                 fmaxf(fmaf(b2f(u[5]), c1.y, h1.y), 0.f));
                    w[3] = pack2(fmaxf(fmaf(b2f(u[6]), c1.z, h1.z), 0.f),
                                 fmaxf(fmaf(b2f(u[7]), c1.w, h1.w), 0.f));
                    short8_t rr;
                    *(uint4*)&rr = *(const uint4*)w;
                    if (z) a1 = rr; else a0 = rr;
                }
            }
            #pragma unroll
            for (int nt = 0; nt < NT; ++nt) {
                short8_t bf = *(const short8_t*)&Bs[(wn * WN + nt * 16 + l16) * 128 + ((j ^ l16) * 8)];
                acc[0][nt] = __builtin_amdgcn_mfma_f32_16x16x32_bf16(a0, bf, acc[0][nt], 0, 0, 0);
                acc[1][nt] = __builtin_amdgcn_mfma_f32_16x16x32_bf16(a1, bf, acc[1][nt], 0, 0, 0);
            }
        }

        #pragma unroll
        for (int mt = 0; mt < 2; ++mt)
            #pragma unroll
            for (int nt = 0; nt < NT; ++nt)
                #pragma unroll
                for (int r = 0; r < 4; ++r) {
                    float v = acc[mt][nt][r] + bvs[nt];
                    acc[mt][nt][r] = v;
                    if (STATS) { sSum[nt] += v; sSq[nt] = fmaf(v, v, sSq[nt]); }
                }
        if (STATS && it == RPT - 1) {
            #pragma unroll
            for (int nt = 0; nt < NT; ++nt) {
                float s = sSum[nt], q = sSq[nt];
                s += __shfl_xor(s, 16); q += __shfl_xor(q, 16);
                s += __shfl_xor(s, 32); q += __shfl_xor(q, 32);
                if (lane < 16) {
                    int col = wn * WN + nt * 16 + l16;
                    sred[(wave * N + col) * 2 + 0] = s;
                    sred[(wave * N + col) * 2 + 1] = q;
                }
            }
        }
        __syncthreads();

        char* eb = (char*)Abuf[it & 1];
        #pragma unroll
        for (int mt = 0; mt < 2; ++mt)
            #pragma unroll
            for (int nt = 0; nt < NT; ++nt) {
                int col = wn * WN + nt * 16 + l16;
                int bc = col * (int)sizeof(CT);
                #pragma unroll
                for (int r = 0; r < 4; ++r) {
                    int row = wm * 32 + mt * 16 + quad * 4 + r;
                    int addr = row * 256 + ((((bc >> 4) ^ (row & 15)) << 4) | (bc & 15));
                    if constexpr (sizeof(CT) == 4) *(float*)(eb + addr) = acc[mt][nt][r];
                    else                           *(ushort_t*)(eb + addr) = f2b(acc[mt][nt][r]);
                }
            }
        if (STATS && it == RPT - 1) {
            int col = tid & (N - 1), qs = tid / N;
            int wb = (col / WN) * 2;
            float v = sred[(wb * N + col) * 2 + qs] + sred[((wb + 1) * N + col) * 2 + qs];
            atomicAdd(accumOut + qs * 128 + col, v);
        }
        __syncthreads();

        int r0 = blockIdx.x * (RPT * 64) + it * 64;
        #pragma unroll
        for (int p = 0; p < 4; ++p) {
            int s = p * 256 + tid;
            int row = s >> 4, gg2 = s & 15;
            uint4 v = *(const uint4*)(eb + row * 256 + ((gg2 ^ (row & 15)) << 4));
            *(uint4*)((char*)(C + (size_t)(r0 + row) * N) + gg2 * 16) = v;
        }
    }
}

// ---------------------------------------------------------------------------
// fp32 vector GEMM (layer 0: K=32, fp32 input), grid-strided over RPT row
// tiles per block. Weights staged ONCE; A-tile async-stage split (issue loads
// early, ds_write late). Stats in registers across tiles -> one LDS reduce +
// 256 atomics per block (512 blocks -> 131K atomics, proven-safe count).
// ---------------------------------------------------------------------------
template<int K, int N, int RPT>
__launch_bounds__(256)
__global__ void gemm_f32_k(const float* __restrict__ A, const float* __restrict__ W,
                           const float* __restrict__ bias, ushort_t* __restrict__ C,
                           float* __restrict__ accum) {
    constexpr int TX = N / 4;        // 32
    constexpr int TY = 256 / TX;     // 8
    constexpr int RM = TILE_M / TY;  // 8

    __shared__ float As[2][TILE_M][BK + 1];
    __shared__ float Ws[BK][N];
    __shared__ float redst[2][TY][N];

    const int tid = threadIdx.x;
    const int tx = tid % TX;
    const int ty = tid / TX;
    const int row0 = blockIdx.x * (RPT * TILE_M);
    const int arow = tid >> 2;
    const int acol = (tid & 3) * 8;

    // ---- stage weights once (K=32 -> whole K fits one tile) ----
    #pragma unroll
    for (int i = 0; i < (BK * N) / 256; ++i) {
        int e = i * 256 + tid;
        Ws[e / N][e % N] = W[(size_t)(e / N) * N + e % N];
    }
    // ---- preload tile 0 A ----
    {
        const float4* p = (const float4*)&A[(size_t)(row0 + arow) * K + acol];
        float4 x0 = p[0], x1 = p[1];
        As[0][arow][acol + 0] = x0.x; As[0][arow][acol + 1] = x0.y;
        As[0][arow][acol + 2] = x0.z; As[0][arow][acol + 3] = x0.w;
        As[0][arow][acol + 4] = x1.x; As[0][arow][acol + 5] = x1.y;
        As[0][arow][acol + 6] = x1.z; As[0][arow][acol + 7] = x1.w;
    }

    float4 bv = *(const float4*)&bias[tx * 4];
    float s[4] = {0, 0, 0, 0}, q[4] = {0, 0, 0, 0};

    for (int it = 0; it < RPT; ++it) {
        __syncthreads();   // As[it&1] (and Ws on it=0) resident
        // issue next tile's loads EARLY (latency hides under FMA loop)
        float4 nx0, nx1;
        if (it + 1 < RPT) {
            const float4* p = (const float4*)&A[(size_t)(row0 + (it + 1) * TILE_M + arow) * K + acol];
            nx0 = p[0]; nx1 = p[1];
        }

        float acc[RM][4];
        #pragma unroll
        for (int r = 0; r < RM; ++r)
            #pragma unroll
            for (int c = 0; c < 4; ++c) acc[r][c] = 0.f;
        #pragma unroll
        for (int kk = 0; kk < BK; ++kk) {
            float4 wv = *(const float4*)&Ws[kk][tx * 4];
            #pragma unroll
            for (int r = 0; r < RM; ++r) {
                float a = As[it & 1][ty * RM + r][kk];
                acc[r][0] = fmaf(a, wv.x, acc[r][0]);
                acc[r][1] = fmaf(a, wv.y, acc[r][1]);
                acc[r][2] = fmaf(a, wv.z, acc[r][2]);
                acc[r][3] = fmaf(a, wv.w, acc[r][3]);
            }
        }

        // bias + stats + coalesced bf16 store for this tile
        #pragma unroll
        for (int r = 0; r < RM; ++r) {
            float o[4];
            o[0] = acc[r][0] + bv.x; o[1] = acc[r][1] + bv.y;
            o[2] = acc[r][2] + bv.z; o[3] = acc[r][3] + bv.w;
            #pragma unroll
            for (int c = 0; c < 4; ++c) { s[c] += o[c]; q[c] = fmaf(o[c], o[c], q[c]); }
            size_t off = (size_t)(row0 + it * TILE_M + ty * RM + r) * N + tx * 4;
            uint2 ov;
            ov.x = pack2(o[0], o[1]);
            ov.y = pack2(o[2], o[3]);
            *(uint2*)&C[off] = ov;
        }

        // ds_write the prefetched tile LATE (vmcnt wait lands after compute)
        if (it + 1 < RPT) {
            int b = (it + 1) & 1;
            As[b][arow][acol + 0] = nx0.x; As[b][arow][acol + 1] = nx0.y;
            As[b][arow][acol + 2] = nx0.z; As[b][arow][acol + 3] = nx0.w;
            As[b][arow][acol + 4] = nx1.x; As[b][arow][acol + 5] = nx1.y;
            As[b][arow][acol + 6] = nx1.z; As[b][arow][acol + 7] = nx1.w;
        }
    }

    __syncthreads();   // As reads done; redst region free
    #pragma unroll
    for (int c = 0; c < 4; ++c) {
        redst[0][ty][tx * 4 + c] = s[c];
        redst[1][ty][tx * 4 + c] = q[c];
    }
    __syncthreads();
    {
        int col = tid & (N - 1), qs = tid / N;
        float v = 0.f;
        #pragma unroll
        for (int t = 0; t < TY; ++t) v += redst[qs][t][col];
        atomicAdd(accum + qs * 128 + col, v);
    }
}

// All four weight transposes in one launch: fp32 W[K][N] -> bf16 WT[N][K]
__global__ void transpose_all_k(const float* __restrict__ W1, const float* __restrict__ W2,
                                const float* __restrict__ W3, const float* __restrict__ W4,
                                ushort_t* __restrict__ wt1, ushort_t* __restrict__ wt2,
                                ushort_t* __restrict__ wt3, ushort_t* __restrict__ wt4) {
    int idx = blockIdx.x * 256 + threadIdx.x;
    if (idx < 32768) {                       // W1: 256 x 128
        int k = idx >> 7, n = idx & 127;
        wt1[(size_t)n * 256 + k] = f2b(W1[idx]);
    } else if (idx < 49152) {                // W2: 128 x 128
        int i = idx - 32768;
        int k = i >> 7, n = i & 127;
        wt2[(size_t)n * 128 + k] = f2b(W2[i]);
    } else if (idx < 65536) {                // W3: 128 x 128
        int i = idx - 49152;
        int k = i >> 7, n = i & 127;
        wt3[(size_t)n * 128 + k] = f2b(W3[i]);
    } else if (idx < 73728) {                // W4: 128 x 64
        int i = idx - 65536;
        int k = i >> 6, n = i & 63;
        wt4[(size_t)n * 128 + k] = f2b(W4[i]);
    }
}

extern "C" void kernel_launch(void* const* d_in, const int* in_sizes, int n_in,
                              void* d_out, int out_size, void* d_ws, size_t ws_size,
                              hipStream_t stream) {
    const float* poly = (const float*)d_in[0];
    const float* W0 = (const float*)d_in[1];
    const float* b0 = (const float*)d_in[2];
    const float* g0 = (const float*)d_in[3];
    const float* be0 = (const float*)d_in[4];
    const float* W1 = (const float*)d_in[5];
    const float* b1 = (const float*)d_in[6];
    const float* g1 = (const float*)d_in[7];
    const float* be1 = (const float*)d_in[8];
    const float* W2 = (const float*)d_in[9];
    const float* b2 = (const float*)d_in[10];
    const float* g2 = (const float*)d_in[11];
    const float* be2 = (const float*)d_in[12];
    const float* W3 = (const float*)d_in[13];
    const float* b3 = (const float*)d_in[14];
    const float* g3 = (const float*)d_in[15];
    const float* be3 = (const float*)d_in[16];
    const float* W4 = (const float*)d_in[17];
    const float* b4 = (const float*)d_in[18];
    float* out = (float*)d_out;

    float* st = (float*)d_ws;
    float* accum = st + 1048576;            // 4 layers x 256 floats
    ushort_t* wt1 = (ushort_t*)((char*)d_ws + 4263936);         // 128 x 256
    ushort_t* wt2 = wt1 + 128 * 256;                            // 128 x 128
    ushort_t* wt3 = wt2 + 128 * 128;                            // 128 x 128
    ushort_t* wt4 = wt3 + 128 * 128;                            // 64 x 128
    ushort_t* h0 = (ushort_t*)((char*)d_ws + 4263936 + 147456);
    ushort_t* y1 = (ushort_t*)out;   // d_out doubles as y1 scratch (M*128 bf16
                                     // == out_size bytes); overwritten by L4.

    const int GP = M_ROWS / (64 * 8);   // 512 (persistent kernels, RPT=8)

    // zero all stat accumulators (4 layers x 256 floats) before any atomics
    hipMemsetAsync(accum, 0, 1024 * sizeof(float), stream);

    // Layer 0 (fp32 precision): y0 = poly @ W0 + b0 -> h0 (raw bf16) + stats(accum)
    gemm_f32_k<32, 128, 8><<<GP, 256, 0, stream>>>(poly, W0, b0, h0, accum);
    transpose_all_k<<<288, 256, 0, stream>>>(W1, W2, W3, W4, wt1, wt2, wt3, wt4);

    // Layer 1 (FUSED scan, XCD-paired): y1 = [bnrelu0(y0), cummax(bnrelu0(y0))]
    //   @ W1 + b1 -> d_out scratch; BN0 finalize folded in; stats -> accum+256
    gemm1s_k<8><<<2 * GP, 256, 0, stream>>>(h0, wt1, b1, g0, be0, accum,
                                            y1, accum + 256);

    // Layer 2: y2 = bnrelu1(y1) @ W2 + b2 : d_out -> h0; stats -> accum+512
    mfma_gemm3_k<128, 1, 1, 8, ushort_t><<<GP, 256, 0, stream>>>(
        y1, wt2, b2, g1, be1, accum + 256, h0, accum + 512);

    // Layer 3 (FUSED scan): y3 = cummax(bnrelu2(y2)) @ W3 + b3 -> h0 in place;
    //   BN2 finalize folded in; stats -> accum+768
    mfma_gemm3_k<128, 2, 1, 8, ushort_t><<<GP, 256, 0, stream>>>(
        h0, wt3, b3, g2, be2, accum + 512, h0, accum + 768);

    // Layer 4: out = bnrelu3(y3) @ W4 + b4 -> d_out (fp32; overwrites y1 scratch)
    mfma_gemm3_k<64, 1, 0, 8, float><<<GP, 256, 0, stream>>>(
        h0, wt4, b4, g3, be3, accum + 768, out, nullptr);
}

// Round 15
// 304.396 us; speedup vs baseline: 1.0451x; 1.0201x over previous
//
#include <hip/hip_runtime.h>
#include <hip/hip_bf16.h>

// Problem constants (fixed by setup_inputs)
#define M_ROWS 262144   // B*A*T = 16*64*256
#define TILE_M 64
#define BK 32
#define INVM (1.0f / 262144.0f)

typedef unsigned short ushort_t;
typedef unsigned int uint_t;
typedef __attribute__((ext_vector_type(8))) short short8_t;   // 8 bf16 = 4 VGPRs
typedef __attribute__((ext_vector_type(4))) float float4_t;   // MFMA acc

// bf16 (stored as ushort) <-> fp32 helpers. Load is exact; store is RNE.
__device__ __forceinline__ float b2f(ushort_t u) {
    union { uint_t i; float f; } c; c.i = ((uint_t)u) << 16; return c.f;
}
__device__ __forceinline__ ushort_t f2b(float f) {
    union { float f; uint_t i; } c; c.f = f;
    uint_t u = c.i;
    return (ushort_t)((u + 0x7fffu + ((u >> 16) & 1u)) >> 16);
}
// packed 2xfp32 -> 2xbf16 (v_cvt_pk_bf16_f32 on gfx950, RNE)
__device__ __forceinline__ uint_t pack2(float a, float b) {
    union { __hip_bfloat162 h; uint_t u; } c;
    c.h = __float22bfloat162_rn(make_float2(a, b));
    return c.u;
}

// async global->LDS DMA, 16 B per lane; data lands at ldsbase + lane*16
__device__ __forceinline__ void gld_lds16(const ushort_t* g, ushort_t* l) {
    __builtin_amdgcn_global_load_lds((const __attribute__((address_space(1))) void*)g,
                                     (__attribute__((address_space(3))) void*)l, 16, 0, 0);
}

// BN finalize arithmetic (shared by all consumers): from accumulated sum/sumsq.
__device__ __forceinline__ void bn_coeff(float s, float q, float g, float be,
                                         float& sc, float& sh) {
    float mean = s * INVM;
    float var = q * INVM - mean * mean;
    sc = g * rsqrtf(var + 1e-5f);
    sh = fmaf(-mean, sc, be);
}

// ---------------------------------------------------------------------------
// Layer-1 N-SPLIT pipelined GEMM with FUSED causal-cummax:
//   C = [bnrelu0(X), cummax(bnrelu0(X))] @ W1 + b1  (K=256), X read ONCE.
// Grid = 1024 blocks; XCD-aware swizzle (T1): logical id lg = (bid&7)*128 +
// (bid>>3) puts logical-contiguous blocks on ONE XCD, so the half-pair
// (2t, 2t+1) — which reads the SAME 64 X-rows — shares that XCD's L2
// (verified r14: FETCH 66->33 MB).
// Per tile: PASS1 = act whole tile IN PLACE (once per element) + local 16-row
// scan into regs + group totals -> kt0 MFMA reads PRE-ACTIVATED frags ->
// PASS2 = prefix-combine + write P in place (+carry) -> kt1 MFMA on P frags.
// Prefetch DMA issued at loop-top. BN coeffs from accumIn (finalize folded);
// stats atomicAdd into accumOut.
// ---------------------------------------------------------------------------
template<int RPT>
__launch_bounds__(256)
__global__ void gemm1s_k(const ushort_t* __restrict__ X,
                         const ushort_t* __restrict__ WT, const float* __restrict__ bias,
                         const float* __restrict__ g, const float* __restrict__ be,
                         const float* __restrict__ accumIn,
                         ushort_t* __restrict__ C, float* __restrict__ accumOut) {
    __shared__ __attribute__((aligned(16))) ushort_t Bs[64 * 256];       // 32 KB
    __shared__ __attribute__((aligned(16))) ushort_t Abuf[2][64 * 128];  // 2x16 KB
    __shared__ float sred[4 * 64 * 2];
    __shared__ float s_sc[128], s_sh[128];
    __shared__ float gtb[4 * 128];    // scan group totals
    __shared__ float carry[128];      // inter-tile scan carry

    const int tid = threadIdx.x;
    const int lane = tid & 63;
    const int wave = tid >> 6;
    const int wm = wave & 1, wn = wave >> 1;
    const int quad = lane >> 4, l16 = lane & 15;
    const int srow = lane >> 4, sp16 = lane & 15;   // A staging
    const int brow = lane >> 5, bs32 = lane & 31;   // B staging (512 B rows)
    const int lg = (blockIdx.x & 7) * 128 + (blockIdx.x >> 3);  // XCD swizzle
    const int tileId = lg >> 1;
    const int n0 = (lg & 1) * 64;                   // column-half offset
    const int row0 = tileId * (RPT * 64);

    if (tid < 128) {
        float sc, sh;
        bn_coeff(accumIn[tid], accumIn[128 + tid], g[tid], be[tid], sc, sh);
        s_sc[tid] = sc; s_sh[tid] = sh;
    }

    // ---- stage B half (rows n0..n0+63 of WT, 512 B each): 32 chunks x 1 KB ----
    #pragma unroll
    for (int i = 0; i < 8; ++i) {
        int t = i * 4 + wave;
        int r = t * 2 + brow;                        // local B row 0..63
        int sp = (bs32 & 16) | ((bs32 ^ r) & 15);    // half-preserving XOR swizzle
        gld_lds16(WT + (size_t)(n0 + r) * 256 + sp * 8, Bs + t * 512);
    }

    auto stageX = [&](int it, int buf) {
        int r0 = row0 + it * 64;
        #pragma unroll
        for (int i = 0; i < 4; ++i) {
            int t = i * 4 + wave;
            int r = t * 4 + srow;
            int sp = sp16 ^ (r & 15);
            gld_lds16(X + (size_t)(r0 + r) * 128 + sp * 8, Abuf[buf] + t * 512);
        }
    };
    stageX(0, 0);

    float bvs[2];
    #pragma unroll
    for (int nt = 0; nt < 2; ++nt) bvs[nt] = bias[n0 + wn * 32 + nt * 16 + l16];
    float sSum[2] = {0.f, 0.f}, sSq[2] = {0.f, 0.f};

    const int j0 = lane >> 2;          // scan addressing: chunk within row
    const int of2 = (lane & 3) * 2;    // ushort offset within chunk (2 cols)
    __syncthreads();   // order s_sc/s_sh writes (tid<128) before hoisted reads
    const float ssc0 = s_sc[2 * lane], ssh0 = s_sh[2 * lane];
    const float ssc1 = s_sc[2 * lane + 1], ssh1 = s_sh[2 * lane + 1];

    for (int it = 0; it < RPT; ++it) {
        __syncthreads();   // (A) X(it) resident; prior epi-store reads done
        if (it + 1 < RPT) stageX(it + 1, (it + 1) & 1);   // DMA overlaps whole tile
        const ushort_t* As = Abuf[it & 1];

        // ---- PASS 1: act whole tile in place + local scan (rows wave*16..+15)
        float pv0[16], pv1[16];
        float base0, base1, lv0 = 0.f, lv1 = 0.f;
        {
            if (it & 3) { base0 = carry[2 * lane]; base1 = carry[2 * lane + 1]; }
            else        { base0 = 0.f; base1 = 0.f; }   // sequence boundary
            ushort_t* Aw = (ushort_t*)Abuf[it & 1];
            #pragma unroll
            for (int i = 0; i < 16; ++i) {
                int r = wave * 16 + i;
                uint_t u = *(const uint_t*)&Aw[r * 128 + ((j0 ^ (r & 15)) * 8) + of2];
                float a0v = fmaxf(fmaf(b2f((ushort_t)(u & 0xffff)), ssc0, ssh0), 0.f);
                float a1v = fmaxf(fmaf(b2f((ushort_t)(u >> 16)), ssc1, ssh1), 0.f);
                *(uint_t*)&Aw[r * 128 + ((j0 ^ (r & 15)) * 8) + of2] = pack2(a0v, a1v);
                lv0 = fmaxf(lv0, a0v);
                lv1 = fmaxf(lv1, a1v);
                pv0[i] = lv0; pv1[i] = lv1;
            }
            gtb[wave * 128 + 2 * lane] = lv0;
            gtb[wave * 128 + 2 * lane + 1] = lv1;
        }
        __syncthreads();   // (B1) act'd tile + group totals visible; carry reads done

        float4_t acc[2][2];
        #pragma unroll
        for (int mt = 0; mt < 2; ++mt)
            #pragma unroll
            for (int nt = 0; nt < 2; ++nt) acc[mt][nt] = (float4_t)0.f;

        // ---- kt0: PRE-ACTIVATED fragments; B kt=0 half (no act block) ----
        #pragma unroll
        for (int kk = 0; kk < 4; ++kk) {
            int j = kk * 4 + quad;
            short8_t a0 = *(const short8_t*)&As[(wm * 32 + l16) * 128 + ((j ^ l16) * 8)];
            short8_t a1 = *(const short8_t*)&As[(wm * 32 + 16 + l16) * 128 + ((j ^ l16) * 8)];
            #pragma unroll
            for (int nt = 0; nt < 2; ++nt) {
                int br = wn * 32 + nt * 16 + l16;
                short8_t bf = *(const short8_t*)&Bs[br * 256 + ((j ^ l16) * 8)];
                acc[0][nt] = __builtin_amdgcn_mfma_f32_16x16x32_bf16(a0, bf, acc[0][nt], 0, 0, 0);
                acc[1][nt] = __builtin_amdgcn_mfma_f32_16x16x32_bf16(a1, bf, acc[1][nt], 0, 0, 0);
            }
        }
        __syncthreads();   // (B2) kt0 fragment reads done

        // ---- PASS 2: prefix-combine + write P in place ----
        {
            float o0 = base0, o1 = base1;
            for (int gg = 0; gg < wave; ++gg) {
                o0 = fmaxf(o0, gtb[gg * 128 + 2 * lane]);
                o1 = fmaxf(o1, gtb[gg * 128 + 2 * lane + 1]);
            }
            if (wave == 3) {   // next-tile carry (old-carry reads were pre-B1)
                carry[2 * lane]     = fmaxf(o0, lv0);
                carry[2 * lane + 1] = fmaxf(o1, lv1);
            }
            ushort_t* Aw = (ushort_t*)Abuf[it & 1];
            #pragma unroll
            for (int i = 0; i < 16; ++i) {
                int r = wave * 16 + i;
                *(uint_t*)&Aw[r * 128 + ((j0 ^ (r & 15)) * 8) + of2] =
                    pack2(fmaxf(pv0[i], o0), fmaxf(pv1[i], o1));
            }
        }
        __syncthreads();   // (C) P visible

        // ---- kt1: P fragments; B kt=1 half ----
        #pragma unroll
        for (int kk = 0; kk < 4; ++kk) {
            int j = kk * 4 + quad;
            short8_t a0 = *(const short8_t*)&As[(wm * 32 + l16) * 128 + ((j ^ l16) * 8)];
            short8_t a1 = *(const short8_t*)&As[(wm * 32 + 16 + l16) * 128 + ((j ^ l16) * 8)];
            #pragma unroll
            for (int nt = 0; nt < 2; ++nt) {
                int br = wn * 32 + nt * 16 + l16;
                short8_t bf = *(const short8_t*)&Bs[br * 256 + 128 + ((j ^ l16) * 8)];
                acc[0][nt] = __builtin_amdgcn_mfma_f32_16x16x32_bf16(a0, bf, acc[0][nt], 0, 0, 0);
                acc[1][nt] = __builtin_amdgcn_mfma_f32_16x16x32_bf16(a1, bf, acc[1][nt], 0, 0, 0);
            }
        }

        // ---- bias + stats accumulate ----
        #pragma unroll
        for (int mt = 0; mt < 2; ++mt)
            #pragma unroll
            for (int nt = 0; nt < 2; ++nt)
                #pragma unroll
                for (int r = 0; r < 4; ++r) {
                    float v = acc[mt][nt][r] + bvs[nt];
                    acc[mt][nt][r] = v;
                    sSum[nt] += v; sSq[nt] = fmaf(v, v, sSq[nt]);
                }
        if (it == RPT - 1) {
            #pragma unroll
            for (int nt = 0; nt < 2; ++nt) {
                float s = sSum[nt], q = sSq[nt];
                s += __shfl_xor(s, 16); q += __shfl_xor(q, 16);
                s += __shfl_xor(s, 32); q += __shfl_xor(q, 32);
                if (lane < 16) {
                    int colL = wn * 32 + nt * 16 + l16;
                    sred[(wave * 64 + colL) * 2 + 0] = s;
                    sred[(wave * 64 + colL) * 2 + 1] = q;
                }
            }
        }
        __syncthreads();   // (D) kt1 reads of Abuf done; sred visible

        // ---- swizzled transpose into Abuf[it&1] (dead after kt1) ----
        char* eb = (char*)Abuf[it & 1];
        #pragma unroll
        for (int mt = 0; mt < 2; ++mt)
            #pragma unroll
            for (int nt = 0; nt < 2; ++nt) {
                int colL = wn * 32 + nt * 16 + l16;
                int bc = colL * 2;
                #pragma unroll
                for (int r = 0; r < 4; ++r) {
                    int row = wm * 32 + mt * 16 + quad * 4 + r;
                    int addr = row * 128 + ((((bc >> 4) ^ (row & 7)) << 4) | (bc & 15));
                    *(ushort_t*)(eb + addr) = f2b(acc[mt][nt][r]);
                }
            }
        if (it == RPT - 1 && tid < 128) {
            int colL = tid & 63, qs = tid >> 6;
            int wb = (colL >> 5) * 2;   // the two waves (wm=0,1) owning this col
            float v = sred[(wb * 64 + colL) * 2 + qs] + sred[((wb + 1) * 64 + colL) * 2 + qs];
            atomicAdd(accumOut + qs * 128 + n0 + colL, v);
        }
        __syncthreads();   // (E) epi tile resident

        // ---- coalesced 16 B stores of the 64-col half (128 B per row) ----
        int r0s = row0 + it * 64;
        #pragma unroll
        for (int p = 0; p < 2; ++p) {
            int s = p * 256 + tid;
            int row = s >> 3, gg2 = s & 7;
            uint4 v = *(const uint4*)(eb + row * 128 + ((gg2 ^ (row & 7)) << 4));
            *(uint4*)((char*)(C + (size_t)(r0s + row) * 128 + n0) + gg2 * 16) = v;
        }
    }
}

// ---------------------------------------------------------------------------
// Persistent pipelined MFMA GEMM for K=128 layers: C = act(A)@W + bias.
// MODE==1: PASS0 act-in-place ONCE per element (r12 pattern; the old
//          per-fragment act was 2x-duplicated across wn-wave pairs and
//          re-read coeffs from LDS per fragment), then plain MFMA.
// MODE==2: FUSED act+causal-cummax via 4-wave segmented scan before MFMA.
// ---------------------------------------------------------------------------
template<int N, int MODE, int STATS, int RPT, typename CT>
__launch_bounds__(256)
__global__ void mfma_gemm3_k(const ushort_t* __restrict__ A, const ushort_t* __restrict__ WT,
                             const float* __restrict__ bias,
                             const float* __restrict__ g, const float* __restrict__ be,
                             const float* __restrict__ accumIn,
                             CT* __restrict__ C, float* __restrict__ accumOut) {
    constexpr int WN = N / 2;        // cols per wave-column (64 or 32)
    constexpr int NT = WN / 16;      // 4 (N=128) or 2 (N=64)

    __shared__ __attribute__((aligned(16))) ushort_t Bs[N * 128];
    __shared__ __attribute__((aligned(16))) ushort_t Abuf[2][64 * 128];
    __shared__ float sred[STATS ? 4 * N * 2 : 1];
    __shared__ float s_sc[MODE >= 1 ? 128 : 1];
    __shared__ float s_sh[MODE >= 1 ? 128 : 1];
    __shared__ float gtb[MODE == 2 ? 4 * 128 : 1];
    __shared__ float carry[MODE == 2 ? 128 : 1];

    const int tid = threadIdx.x;
    const int lane = tid & 63;
    const int wave = tid >> 6;
    const int wm = wave & 1;
    const int wn = wave >> 1;
    const int quad = lane >> 4;
    const int l16 = lane & 15;
    const int srow = lane >> 4;
    const int sp16 = lane & 15;

    if (MODE >= 1 && tid < 128) {
        float sc, sh;
        bn_coeff(accumIn[tid], accumIn[128 + tid], g[tid], be[tid], sc, sh);
        s_sc[tid] = sc; s_sh[tid] = sh;
    }

    #pragma unroll
    for (int i = 0; i < N / 16; ++i) {
        int t = i * 4 + wave;
        int r = t * 4 + srow;
        int sp = sp16 ^ (r & 15);
        gld_lds16(WT + (size_t)r * 128 + sp * 8, Bs + t * 512);
    }
    {
        int r0 = blockIdx.x * (RPT * 64);
        #pragma unroll
        for (int i = 0; i < 4; ++i) {
            int t = i * 4 + wave;
            int r = t * 4 + srow;
            int sp = sp16 ^ (r & 15);
            gld_lds16(A + (size_t)(r0 + r) * 128 + sp * 8, Abuf[0] + t * 512);
        }
    }

    float bvs[NT];
    #pragma unroll
    for (int nt = 0; nt < NT; ++nt) bvs[nt] = bias[wn * WN + nt * 16 + l16];
    float sSum[STATS ? NT : 1] = {0.f}, sSq[STATS ? NT : 1] = {0.f};

    const int j0 = lane >> 2;
    const int of2 = (lane & 3) * 2;

    for (int it = 0; it < RPT; ++it) {
        __syncthreads();   // tile resident; prior epi-store reads done

        if (it + 1 < RPT) {
            int r0 = blockIdx.x * (RPT * 64) + (it + 1) * 64;
            #pragma unroll
            for (int i = 0; i < 4; ++i) {
                int t = i * 4 + wave;
                int r = t * 4 + srow;
                int sp = sp16 ^ (r & 15);
                gld_lds16(A + (size_t)(r0 + r) * 128 + sp * 8, Abuf[(it + 1) & 1] + t * 512);
            }
        }

        if constexpr (MODE == 1) {
            // ---- PASS0: act tile in place, once per element (no scan) ----
            float ssc0 = s_sc[2 * lane], ssh0 = s_sh[2 * lane];
            float ssc1 = s_sc[2 * lane + 1], ssh1 = s_sh[2 * lane + 1];
            ushort_t* Aw = (ushort_t*)Abuf[it & 1];
            #pragma unroll
            for (int i = 0; i < 16; ++i) {
                int r = wave * 16 + i;
                uint_t u = *(const uint_t*)&Aw[r * 128 + ((j0 ^ (r & 15)) * 8) + of2];
                float a0v = fmaxf(fmaf(b2f((ushort_t)(u & 0xffff)), ssc0, ssh0), 0.f);
                float a1v = fmaxf(fmaf(b2f((ushort_t)(u >> 16)), ssc1, ssh1), 0.f);
                *(uint_t*)&Aw[r * 128 + ((j0 ^ (r & 15)) * 8) + of2] = pack2(a0v, a1v);
            }
            __syncthreads();   // act'd tile visible to all waves
        }

        if constexpr (MODE == 2) {
            // ---- 4-wave segmented scan: pass 1 (local act+cummax) ----
            float pv0[16], pv1[16];
            float base0, base1, lv0 = 0.f, lv1 = 0.f;
            float ssc0 = s_sc[2 * lane], ssh0 = s_sh[2 * lane];
            float ssc1 = s_sc[2 * lane + 1], ssh1 = s_sh[2 * lane + 1];
            {
                if (it & 3) { base0 = carry[2 * lane]; base1 = carry[2 * lane + 1]; }
                else        { base0 = 0.f; base1 = 0.f; }
                ushort_t* Aw = (ushort_t*)Abuf[it & 1];
                #pragma unroll
                for (int i = 0; i < 16; ++i) {
                    int r = wave * 16 + i;
                    uint_t u = *(const uint_t*)&Aw[r * 128 + ((j0 ^ (r & 15)) * 8) + of2];
                    lv0 = fmaxf(lv0, fmaxf(fmaf(b2f((ushort_t)(u & 0xffff)), ssc0, ssh0), 0.f));
                    lv1 = fmaxf(lv1, fmaxf(fmaf(b2f((ushort_t)(u >> 16)), ssc1, ssh1), 0.f));
                    pv0[i] = lv0; pv1[i] = lv1;
                }
                gtb[wave * 128 + 2 * lane] = lv0;
                gtb[wave * 128 + 2 * lane + 1] = lv1;
            }
            __syncthreads();   // group totals visible; carry reads done
            {
                float o0 = base0, o1 = base1;
                for (int gg = 0; gg < wave; ++gg) {
                    o0 = fmaxf(o0, gtb[gg * 128 + 2 * lane]);
                    o1 = fmaxf(o1, gtb[gg * 128 + 2 * lane + 1]);
                }
                if (wave == 3) {
                    carry[2 * lane]     = fmaxf(o0, lv0);
                    carry[2 * lane + 1] = fmaxf(o1, lv1);
                }
                ushort_t* Aw = (ushort_t*)Abuf[it & 1];
                #pragma unroll
                for (int i = 0; i < 16; ++i) {
                    int r = wave * 16 + i;
                    *(uint_t*)&Aw[r * 128 + ((j0 ^ (r & 15)) * 8) + of2] =
                        pack2(fmaxf(pv0[i], o0), fmaxf(pv1[i], o1));
                }
            }
            __syncthreads();   // P visible to all waves
        }

        const ushort_t* As = Abuf[it & 1];

        float4_t acc[2][NT];
        #pragma unroll
        for (int mt = 0; mt < 2; ++mt)
            #pragma unroll
            for (int nt = 0; nt < NT; ++nt) acc[mt][nt] = (float4_t)0.f;

        #pragma unroll
        for (int kk = 0; kk < 4; ++kk) {
            int j = kk * 4 + quad;
            short8_t a0 = *(const short8_t*)&As[(wm * 32 + l16) * 128 + ((j ^ l16) * 8)];
            short8_t a1 = *(const short8_t*)&As[(wm * 32 + 16 + l16) * 128 + ((j ^ l16) * 8)];
            #pragma unroll
            for (int nt = 0; nt < NT; ++nt) {
                short8_t bf = *(const short8_t*)&Bs[(wn * WN + nt * 16 + l16) * 128 + ((j ^ l16) * 8)];
                acc[0][nt] = __builtin_amdgcn_mfma_f32_16x16x32_bf16(a0, bf, acc[0][nt], 0, 0, 0);
                acc[1][nt] = __builtin_amdgcn_mfma_f32_16x16x32_bf16(a1, bf, acc[1][nt], 0, 0, 0);
            }
        }

        #pragma unroll
        for (int mt = 0; mt < 2; ++mt)
            #pragma unroll
            for (int nt = 0; nt < NT; ++nt)
                #pragma unroll
                for (int r = 0; r < 4; ++r) {
                    float v = acc[mt][nt][r] + bvs[nt];
                    acc[mt][nt][r] = v;
                    if (STATS) { sSum[nt] += v; sSq[nt] = fmaf(v, v, sSq[nt]); }
                }
        if (STATS && it == RPT - 1) {
            #pragma unroll
            for (int nt = 0; nt < NT; ++nt) {
                float s = sSum[nt], q = sSq[nt];
                s += __shfl_xor(s, 16); q += __shfl_xor(q, 16);
                s += __shfl_xor(s, 32); q += __shfl_xor(q, 32);
                if (lane < 16) {
                    int col = wn * WN + nt * 16 + l16;
                    sred[(wave * N + col) * 2 + 0] = s;
                    sred[(wave * N + col) * 2 + 1] = q;
                }
            }
        }
        __syncthreads();

        char* eb = (char*)Abuf[it & 1];
        #pragma unroll
        for (int mt = 0; mt < 2; ++mt)
            #pragma unroll
            for (int nt = 0; nt < NT; ++nt) {
                int col = wn * WN + nt * 16 + l16;
                int bc = col * (int)sizeof(CT);
                #pragma unroll
                for (int r = 0; r < 4; ++r) {
                    int row = wm * 32 + mt * 16 + quad * 4 + r;
                    int addr = row * 256 + ((((bc >> 4) ^ (row & 15)) << 4) | (bc & 15));
                    if constexpr (sizeof(CT) == 4) *(float*)(eb + addr) = acc[mt][nt][r];
                    else                           *(ushort_t*)(eb + addr) = f2b(acc[mt][nt][r]);
                }
            }
        if (STATS && it == RPT - 1) {
            int col = tid & (N - 1), qs = tid / N;
            int wb = (col / WN) * 2;
            float v = sred[(wb * N + col) * 2 + qs] + sred[((wb + 1) * N + col) * 2 + qs];
            atomicAdd(accumOut + qs * 128 + col, v);
        }
        __syncthreads();

        int r0 = blockIdx.x * (RPT * 64) + it * 64;
        #pragma unroll
        for (int p = 0; p < 4; ++p) {
            int s = p * 256 + tid;
            int row = s >> 4, gg2 = s & 15;
            uint4 v = *(const uint4*)(eb + row * 256 + ((gg2 ^ (row & 15)) << 4));
            *(uint4*)((char*)(C + (size_t)(r0 + row) * N) + gg2 * 16) = v;
        }
    }
}

// ---------------------------------------------------------------------------
// fp32 vector GEMM (layer 0: K=32, fp32 input), grid-strided over RPT row
// tiles per block. Weights staged ONCE; A-tile async-stage split (issue loads
// early, ds_write late). Stats in registers across tiles -> one LDS reduce +
// 256 atomics per block (512 blocks -> 131K atomics, proven-safe count).
// ---------------------------------------------------------------------------
template<int K, int N, int RPT>
__launch_bounds__(256)
__global__ void gemm_f32_k(const float* __restrict__ A, const float* __restrict__ W,
                           const float* __restrict__ bias, ushort_t* __restrict__ C,
                           float* __restrict__ accum) {
    constexpr int TX = N / 4;        // 32
    constexpr int TY = 256 / TX;     // 8
    constexpr int RM = TILE_M / TY;  // 8

    __shared__ float As[2][TILE_M][BK + 1];
    __shared__ float Ws[BK][N];
    __shared__ float redst[2][TY][N];

    const int tid = threadIdx.x;
    const int tx = tid % TX;
    const int ty = tid / TX;
    const int row0 = blockIdx.x * (RPT * TILE_M);
    const int arow = tid >> 2;
    const int acol = (tid & 3) * 8;

    // ---- stage weights once (K=32 -> whole K fits one tile) ----
    #pragma unroll
    for (int i = 0; i < (BK * N) / 256; ++i) {
        int e = i * 256 + tid;
        Ws[e / N][e % N] = W[(size_t)(e / N) * N + e % N];
    }
    // ---- preload tile 0 A ----
    {
        const float4* p = (const float4*)&A[(size_t)(row0 + arow) * K + acol];
        float4 x0 = p[0], x1 = p[1];
        As[0][arow][acol + 0] = x0.x; As[0][arow][acol + 1] = x0.y;
        As[0][arow][acol + 2] = x0.z; As[0][arow][acol + 3] = x0.w;
        As[0][arow][acol + 4] = x1.x; As[0][arow][acol + 5] = x1.y;
        As[0][arow][acol + 6] = x1.z; As[0][arow][acol + 7] = x1.w;
    }

    float4 bv = *(const float4*)&bias[tx * 4];
    float s[4] = {0, 0, 0, 0}, q[4] = {0, 0, 0, 0};

    for (int it = 0; it < RPT; ++it) {
        __syncthreads();   // As[it&1] (and Ws on it=0) resident
        // issue next tile's loads EARLY (latency hides under FMA loop)
        float4 nx0, nx1;
        if (it + 1 < RPT) {
            const float4* p = (const float4*)&A[(size_t)(row0 + (it + 1) * TILE_M + arow) * K + acol];
            nx0 = p[0]; nx1 = p[1];
        }

        float acc[RM][4];
        #pragma unroll
        for (int r = 0; r < RM; ++r)
            #pragma unroll
            for (int c = 0; c < 4; ++c) acc[r][c] = 0.f;
        #pragma unroll
        for (int kk = 0; kk < BK; ++kk) {
            float4 wv = *(const float4*)&Ws[kk][tx * 4];
            #pragma unroll
            for (int r = 0; r < RM; ++r) {
                float a = As[it & 1][ty * RM + r][kk];
                acc[r][0] = fmaf(a, wv.x, acc[r][0]);
                acc[r][1] = fmaf(a, wv.y, acc[r][1]);
                acc[r][2] = fmaf(a, wv.z, acc[r][2]);
                acc[r][3] = fmaf(a, wv.w, acc[r][3]);
            }
        }

        // bias + stats + coalesced bf16 store for this tile
        #pragma unroll
        for (int r = 0; r < RM; ++r) {
            float o[4];
            o[0] = acc[r][0] + bv.x; o[1] = acc[r][1] + bv.y;
            o[2] = acc[r][2] + bv.z; o[3] = acc[r][3] + bv.w;
            #pragma unroll
            for (int c = 0; c < 4; ++c) { s[c] += o[c]; q[c] = fmaf(o[c], o[c], q[c]); }
            size_t off = (size_t)(row0 + it * TILE_M + ty * RM + r) * N + tx * 4;
            uint2 ov;
            ov.x = pack2(o[0], o[1]);
            ov.y = pack2(o[2], o[3]);
            *(uint2*)&C[off] = ov;
        }

        // ds_write the prefetched tile LATE (vmcnt wait lands after compute)
        if (it + 1 < RPT) {
            int b = (it + 1) & 1;
            As[b][arow][acol + 0] = nx0.x; As[b][arow][acol + 1] = nx0.y;
            As[b][arow][acol + 2] = nx0.z; As[b][arow][acol + 3] = nx0.w;
            As[b][arow][acol + 4] = nx1.x; As[b][arow][acol + 5] = nx1.y;
            As[b][arow][acol + 6] = nx1.z; As[b][arow][acol + 7] = nx1.w;
        }
    }

    __syncthreads();   // As reads done; redst region free
    #pragma unroll
    for (int c = 0; c < 4; ++c) {
        redst[0][ty][tx * 4 + c] = s[c];
        redst[1][ty][tx * 4 + c] = q[c];
    }
    __syncthreads();
    {
        int col = tid & (N - 1), qs = tid / N;
        float v = 0.f;
        #pragma unroll
        for (int t = 0; t < TY; ++t) v += redst[qs][t][col];
        atomicAdd(accum + qs * 128 + col, v);
    }
}

// All four weight transposes in one launch: fp32 W[K][N] -> bf16 WT[N][K]
__global__ void transpose_all_k(const float* __restrict__ W1, const float* __restrict__ W2,
                                const float* __restrict__ W3, const float* __restrict__ W4,
                                ushort_t* __restrict__ wt1, ushort_t* __restrict__ wt2,
                                ushort_t* __restrict__ wt3, ushort_t* __restrict__ wt4) {
    int idx = blockIdx.x * 256 + threadIdx.x;
    if (idx < 32768) {                       // W1: 256 x 128
        int k = idx >> 7, n = idx & 127;
        wt1[(size_t)n * 256 + k] = f2b(W1[idx]);
    } else if (idx < 49152) {                // W2: 128 x 128
        int i = idx - 32768;
        int k = i >> 7, n = i & 127;
        wt2[(size_t)n * 128 + k] = f2b(W2[i]);
    } else if (idx < 65536) {                // W3: 128 x 128
        int i = idx - 49152;
        int k = i >> 7, n = i & 127;
        wt3[(size_t)n * 128 + k] = f2b(W3[i]);
    } else if (idx < 73728) {                // W4: 128 x 64
        int i = idx - 65536;
        int k = i >> 6, n = i & 63;
        wt4[(size_t)n * 128 + k] = f2b(W4[i]);
    }
}

extern "C" void kernel_launch(void* const* d_in, const int* in_sizes, int n_in,
                              void* d_out, int out_size, void* d_ws, size_t ws_size,
                              hipStream_t stream) {
    const float* poly = (const float*)d_in[0];
    const float* W0 = (const float*)d_in[1];
    const float* b0 = (const float*)d_in[2];
    const float* g0 = (const float*)d_in[3];
    const float* be0 = (const float*)d_in[4];
    const float* W1 = (const float*)d_in[5];
    const float* b1 = (const float*)d_in[6];
    const float* g1 = (const float*)d_in[7];
    const float* be1 = (const float*)d_in[8];
    const float* W2 = (const float*)d_in[9];
    const float* b2 = (const float*)d_in[10];
    const float* g2 = (const float*)d_in[11];
    const float* be2 = (const float*)d_in[12];
    const float* W3 = (const float*)d_in[13];
    const float* b3 = (const float*)d_in[14];
    const float* g3 = (const float*)d_in[15];
    const float* be3 = (const float*)d_in[16];
    const float* W4 = (const float*)d_in[17];
    const float* b4 = (const float*)d_in[18];
    float* out = (float*)d_out;

    float* st = (float*)d_ws;
    float* accum = st + 1048576;            // 4 layers x 256 floats
    ushort_t* wt1 = (ushort_t*)((char*)d_ws + 4263936);         // 128 x 256
    ushort_t* wt2 = wt1 + 128 * 256;                            // 128 x 128
    ushort_t* wt3 = wt2 + 128 * 128;                            // 128 x 128
    ushort_t* wt4 = wt3 + 128 * 128;                            // 64 x 128
    ushort_t* h0 = (ushort_t*)((char*)d_ws + 4263936 + 147456);
    ushort_t* y1 = (ushort_t*)out;   // d_out doubles as y1 scratch (M*128 bf16
                                     // == out_size bytes); overwritten by L4.

    const int GP = M_ROWS / (64 * 8);   // 512 (persistent kernels, RPT=8)

    // zero all stat accumulators (4 layers x 256 floats) before any atomics
    hipMemsetAsync(accum, 0, 1024 * sizeof(float), stream);

    // Layer 0 (fp32 precision): y0 = poly @ W0 + b0 -> h0 (raw bf16) + stats(accum)
    gemm_f32_k<32, 128, 8><<<GP, 256, 0, stream>>>(poly, W0, b0, h0, accum);
    transpose_all_k<<<288, 256, 0, stream>>>(W1, W2, W3, W4, wt1, wt2, wt3, wt4);

    // Layer 1 (FUSED scan, XCD-paired): y1 = [bnrelu0(y0), cummax(bnrelu0(y0))]
    //   @ W1 + b1 -> d_out scratch; BN0 finalize folded in; stats -> accum+256
    gemm1s_k<8><<<2 * GP, 256, 0, stream>>>(h0, wt1, b1, g0, be0, accum,
                                            y1, accum + 256);

    // Layer 2: y2 = bnrelu1(y1) @ W2 + b2 : d_out -> h0; stats -> accum+512
    mfma_gemm3_k<128, 1, 1, 8, ushort_t><<<GP, 256, 0, stream>>>(
        y1, wt2, b2, g1, be1, accum + 256, h0, accum + 512);

    // Layer 3 (FUSED scan): y3 = cummax(bnrelu2(y2)) @ W3 + b3 -> h0 in place;
    //   BN2 finalize folded in; stats -> accum+768
    mfma_gemm3_k<128, 2, 1, 8, ushort_t><<<GP, 256, 0, stream>>>(
        h0, wt3, b3, g2, be2, accum + 512, h0, accum + 768);

    // Layer 4: out = bnrelu3(y3) @ W4 + b4 -> d_out (fp32; overwrites y1 scratch)
    mfma_gemm3_k<64, 1, 0, 8, float><<<GP, 256, 0, stream>>>(
        h0, wt4, b4, g3, be3, accum + 768, out, nullptr);
}